// Round 10
// baseline (304.977 us; speedup 1.0000x reference)
//
#include <hip/hip_runtime.h>
#include <math.h>

#define BB 8
#define LL 1900
#define LPAD 1920
#define EE 256
#define HH 8
#define DD 32
#define MTOK (BB*LL)              // 15200
#define SCALE 0.17677669529663687f
#define LOG2E 1.4426950408889634f
#define NKB 120                   // keyblocks of 16 per (b,h)
#define BHST (NKB*2*256)          // 61440 shorts per (b,h) in v4

typedef __attribute__((ext_vector_type(8))) short bf16x8;
typedef __attribute__((ext_vector_type(4))) short bf16x4;
typedef __attribute__((ext_vector_type(4))) float floatx4;
typedef __attribute__((ext_vector_type(2))) unsigned uintx2;

__device__ inline short f2bf(float f) {
  unsigned u = __builtin_bit_cast(unsigned, f);
  u += 0x7FFF + ((u >> 16) & 1);
  return (short)(u >> 16);
}

// pack 4 fp32 -> 4 bf16 (truncate) via v_perm_b32
__device__ inline bf16x4 pack4(float s0, float s1, float s2, float s3) {
  uintx2 u;
  u.x = __builtin_amdgcn_perm(__builtin_bit_cast(unsigned, s1),
                              __builtin_bit_cast(unsigned, s0), 0x07060302u);
  u.y = __builtin_amdgcn_perm(__builtin_bit_cast(unsigned, s3),
                              __builtin_bit_cast(unsigned, s2), 0x07060302u);
  return __builtin_bit_cast(bf16x4, u);
}

// async global->LDS DMA, 16 B per lane; lds base must be wave-uniform
__device__ inline void load_lds16(const void* g, void* l) {
  __builtin_amdgcn_global_load_lds(
      (const __attribute__((address_space(1))) unsigned*)g,
      (__attribute__((address_space(3))) unsigned*)l, 16, 0, 0);
}

// ---------------- Kernel 0: fp32 -> bf16 for in_proj_w, out_w, AND x ------
// x lands padded: [XROWS][XSTR] bf16, XSTR=264 shorts (528 B = 33*16 B:
// 16B-multiple for linear DMA; 132 dw == 4 (mod 32) -> 2-way-free banks
// for the stride-XSTR A-fragment reads). Rows >= MTOK zero-filled.
#define CVT_W4  49152             // 196608/4
#define CVT_OW4 16384             // 65536/4
#define XROWS 15264
#define XSTR  264
#define CVT_X4 (XROWS*64)         // 976896
#define CVT_TOT (CVT_W4 + CVT_OW4 + CVT_X4)   // 1042432 = 4072*256
__global__ __launch_bounds__(256) void cvt_kernel(
    const float* __restrict__ w, const float* __restrict__ ow,
    const float* __restrict__ x,
    short* __restrict__ wb, short* __restrict__ owb, short* __restrict__ xb) {
  int i = blockIdx.x * 256 + threadIdx.x;
  if (i < CVT_W4 + CVT_OW4) {
    const float* src; short* dst; int off;
    if (i < CVT_W4) { src = w; dst = wb; off = i; }
    else { src = ow; dst = owb; off = i - CVT_W4; }
    float4 v = *(const float4*)(src + (size_t)off * 4);
    short4 o;
    o.x = f2bf(v.x); o.y = f2bf(v.y); o.z = f2bf(v.z); o.w = f2bf(v.w);
    *(short4*)(dst + (size_t)off * 4) = o;
  } else {
    int j = i - (CVT_W4 + CVT_OW4);
    int row = j >> 6, seg = j & 63;
    short4 o; o.x = 0; o.y = 0; o.z = 0; o.w = 0;
    if (row < MTOK) {
      float4 v = *(const float4*)(x + (size_t)row * EE + seg * 4);
      o.x = f2bf(v.x); o.y = f2bf(v.y); o.z = f2bf(v.z); o.w = f2bf(v.w);
    }
    *(short4*)(xb + (size_t)row * XSTR + seg * 4) = o;
  }
}

// ---------------- Kernel A: QKV projection, LDS-shared w, A-in-regs -------
#define XWSH (16*XSTR)            // 4224 shorts per wave x-slice
#define LDS_SH 17280              // 34,560 B: fits x-slices / w-tile / cbuf
__global__ __launch_bounds__(256, 4) void qkv_kernel(
    const short* __restrict__ xbf, const short* __restrict__ w,
    const float* __restrict__ bias, short* __restrict__ q,
    short* __restrict__ k, short* __restrict__ v4) {
  __shared__ short lds[LDS_SH];
  int bid = blockIdx.x;
  int mtile = bid % 240, npair = bid / 240;   // npair 0..5 -> ntiles 2p,2p+1
  if (mtile >= 238) return;
  int wv = threadIdx.x >> 6, lane = threadIdx.x & 63;
  int l15 = lane & 15, quad = lane >> 4;

  // ---- DMA phase: 16 bf16 rows = 8448 B/wave, 9 x 1 KB linear chunks ----
  const short* gsrc = xbf + (size_t)(mtile * 64 + wv * 16) * XSTR;
  char* xw = (char*)&lds[wv * XWSH];
#pragma unroll
  for (int i = 0; i < 9; ++i)
    load_lds16((const char*)gsrc + i * 1024 + lane * 16, xw + i * 1024);
  asm volatile("s_waitcnt vmcnt(0)" ::: "memory");

  // ---- A-fragments to registers (wave-private slice; no barrier needed) --
  bf16x8 af[8];
#pragma unroll
  for (int ks = 0; ks < 8; ++ks)
    af[ks] = *(const bf16x8*)&lds[wv * XWSH + l15 * XSTR + ks * 32 + quad * 8];
  __syncthreads();   // all A-reads done before w-tile overwrites lds

  floatx4 accs[2][4];
#pragma unroll
  for (int s = 0; s < 2; ++s)
#pragma unroll
    for (int i = 0; i < 4; ++i) accs[s][i] = (floatx4){0.f, 0.f, 0.f, 0.f};

#pragma unroll
  for (int s = 0; s < 2; ++s) {
    int ntile = npair * 2 + s;
    // stage 64x256 w-tile -> padded [64][XSTR] (coalesced global reads)
    const short* wsub = w + (size_t)ntile * 64 * EE;
#pragma unroll
    for (int i = 0; i < 8; ++i) {
      int c = threadIdx.x + i * 256;      // 0..2047 16B-chunks
      int row = c >> 5, col = (c & 31) * 8;
      *(bf16x8*)&lds[row * XSTR + col] = *(const bf16x8*)(wsub + row * EE + col);
    }
    __syncthreads();
#pragma unroll
    for (int ks = 0; ks < 8; ++ks)
#pragma unroll
      for (int ns = 0; ns < 4; ++ns) {
        bf16x8 bfr = *(const bf16x8*)&lds[(ns * 16 + l15) * XSTR + ks * 32 + quad * 8];
        accs[s][ns] = __builtin_amdgcn_mfma_f32_16x16x32_bf16(af[ks], bfr, accs[s][ns], 0, 0, 0);
      }
    __syncthreads();   // done reading w-tile before restage / cbuf reuse
  }

  // ---- epilogue per sub-ntile: bias(+scale), LDS transpose, stores ----
  short* cbuf = (short*)lds;               // 64*72 shorts, aliases lds
  int t0tok = mtile * 64;
  int b0 = t0tok / LL;
  bool uni = (b0 == (t0tok + 63) / LL) && (t0tok + 63 < MTOK);

#pragma unroll
  for (int s = 0; s < 2; ++s) {
    int ntile = npair * 2 + s;
    float qs = (ntile < 4) ? (SCALE * LOG2E) : 1.0f;
#pragma unroll
    for (int ns = 0; ns < 4; ++ns) {
      float bv = bias[ntile * 64 + ns * 16 + l15];
#pragma unroll
      for (int r = 0; r < 4; ++r)
        cbuf[(wv * 16 + quad * 4 + r) * 72 + ns * 16 + l15] =
            f2bf((accs[s][ns][r] + bv) * qs);
    }
    __syncthreads();

    int which = ntile >> 2;          // 0=q 1=k 2=v
    int fbase = (ntile & 3) * 64;

    if (which < 2) {
      short* dst0 = which ? k : q;
      int tl = threadIdx.x >> 2, seg = threadIdx.x & 3;
      int tok = t0tok + tl;
      if (tok < MTOK) {
        int b = uni ? b0 : tok / LL;
        int l = tok - b * LL;
        int fl = seg * 16;
        int h = (fbase + fl) >> 5;
        int d = (fbase + fl) & 31;
        size_t base = ((size_t)(b * HH + h) * LPAD + l) * DD + d;
        bf16x8 v0 = *(bf16x8*)(&cbuf[tl * 72 + fl]);
        bf16x8 v1 = *(bf16x8*)(&cbuf[tl * 72 + fl + 8]);
        *(bf16x8*)(dst0 + base) = v0;
        *(bf16x8*)(dst0 + base + 8) = v1;
      }
    } else {
      // V -> fragment layout v4
      int fl = threadIdx.x >> 2, ls = threadIdx.x & 3;
      int h = (fbase + fl) >> 5;
      int d = (fbase + fl) & 31;
      int db = d >> 4, dl = d & 15;
      if (uni) {
        int l0 = t0tok - b0 * LL + ls * 16;   // 4-aligned (1900 % 4 == 0)
        short* Vb = v4 + (size_t)(b0 * HH + h) * BHST;
#pragma unroll
        for (int g4 = 0; g4 < 4; ++g4) {
          int l = l0 + g4 * 4;
          int kb = l >> 4, qd = (l >> 2) & 3; // l&3 == 0
          int tb = ls * 16 + g4 * 4;
          short4 vv;
          vv.x = cbuf[(tb + 0) * 72 + fl];
          vv.y = cbuf[(tb + 1) * 72 + fl];
          vv.z = cbuf[(tb + 2) * 72 + fl];
          vv.w = cbuf[(tb + 3) * 72 + fl];
          *(short4*)(Vb + (size_t)(kb * 2 + db) * 256 + (dl + 16 * qd) * 4) = vv;
        }
      } else {
#pragma unroll
        for (int i = 0; i < 16; ++i) {
          int tl = ls * 16 + i;
          int tok = t0tok + tl;
          if (tok < MTOK) {
            int b = tok / LL;
            int l = tok - b * LL;
            int kb = l >> 4, qd = (l >> 2) & 3, j = l & 3;
            v4[(size_t)(b * HH + h) * BHST + (size_t)(kb * 2 + db) * 256 +
               (dl + 16 * qd) * 4 + j] = cbuf[tl * 72 + fl];
          }
        }
      }
    }
    __syncthreads();   // cbuf free before next sub-ntile overwrites it
  }
}

// ---------------- Kernel B: flash attention, key-split waves --------------
// Scores are exp2'd with NO running max -> partial (ot, li) over disjoint
// key sets combine LINEARLY. 4-wave blocks: wave = (rowhalf, keyhalf);
// each wave covers its 32 rows over every OTHER tile (parity split over
// the group+band tile list, balanced +-1). Wave count doubles vs R9
// (3840 -> 7680 = 7.5/SIMD) -- R9 was wave-starved (VALUBusy 40% at 2.4
// waves/SIMD, no barriers in the hot loop). End: keyhalf-1 waves dump
// ot/lacc to LDS, one barrier, keyhalf-0 waves add + normalize + store.
__global__ __launch_bounds__(256, 8) void attn_kernel(
    const short* __restrict__ q, const short* __restrict__ k,
    const short* __restrict__ v4, short* __restrict__ ctx,
    const int* __restrict__ pad_size_p, const int* __restrict__ single_pad_p) {
  __shared__ float comb[2][64][24];   // 12,288 B (16B-aligned per lane)
  int bid = blockIdx.x;
  int bh = bid & 63, slot2 = bid >> 6;   // bh fastest -> 8 heads/XCD (L2 fit)
  int wv = threadIdx.x >> 6, lane = threadIdx.x & 63;
  int rowhalf = wv & 1, keyhalf = wv >> 1;
  int l15 = lane & 15, quad = lane >> 4;

  int ps = pad_size_p[0];
  int sp2 = 2 * single_pad_p[0];
  int t0 = ps >> 6;                  // 15
  int kb0 = t0 * 64;                 // 960

  const short* Q = q + (size_t)bh * LPAD * DD;
  const short* K = k + (size_t)bh * LPAD * DD;
  const short* V4 = v4 + (size_t)bh * BHST;
  int lane4 = lane * 4;

  int row0 = slot2 * 64 + rowhalf * 32;   // 32 rows per wave-pair

  bf16x8 qf[2];
  qf[0] = *(const bf16x8*)(Q + (size_t)(row0 + l15) * DD + quad * 8);
  qf[1] = *(const bf16x8*)(Q + (size_t)(row0 + 16 + l15) * DD + quad * 8);

  // per-lane group window (for masking)
  int glo[2], ghi[2];
  // per-half uniform group span (for slice skipping)
  int fg_lo[2], fg_hi[2];
#pragma unroll
  for (int f = 0; f < 2; ++f) {
    int row = row0 + f * 16 + l15;
    int g = row / sp2;
    int lo = g * sp2, hi = lo + sp2;
    if (row >= ps) { lo = 0; hi = 0; }
    glo[f] = lo; ghi[f] = hi;
    int first = row0 + f * 16, last = first + 15;
    if (first >= ps) { fg_lo[f] = 0; fg_hi[f] = 0; }
    else { fg_lo[f] = (first / sp2) * sp2; fg_hi[f] = (last / sp2) * sp2 + sp2; }
  }

  floatx4 lacc[2];
  lacc[0] = (floatx4){0.f, 0.f, 0.f, 0.f};
  lacc[1] = (floatx4){0.f, 0.f, 0.f, 0.f};
  floatx4 ot[2][2];
#pragma unroll
  for (int f = 0; f < 2; ++f)
#pragma unroll
    for (int db = 0; db < 2; ++db) ot[f][db] = (floatx4){0.f, 0.f, 0.f, 0.f};
  const floatx4 zf = (floatx4){0.f, 0.f, 0.f, 0.f};

  // one 64-key tile. mode: 0 = band-clean, 1 = band edge (ps/LL), 2 = group
  auto tile_work = [&](int kbase, int mode) {
    const short* vp = V4 + (size_t)(kbase >> 4) * 512;        // tile base
    const short* kp = K + (size_t)kbase * DD + l15 * DD + quad * 8;
    bf16x8 ka[4];
    bf16x4 va[2][4];
#pragma unroll
    for (int ns = 0; ns < 4; ++ns)
      ka[ns] = *(const bf16x8*)(kp + ns * 512);   // 16 keys * 32 shorts
#pragma unroll
    for (int db = 0; db < 2; ++db)
#pragma unroll
      for (int ns = 0; ns < 4; ++ns)
        va[db][ns] = *(const bf16x4*)(vp + (ns * 2 + db) * 256 + lane4);

    bool act[2][4];
    bf16x4 pt[2][4];
#pragma unroll
    for (int ns = 0; ns < 4; ++ns) {
      int ks0 = kbase + ns * 16;
#pragma unroll
      for (int f = 0; f < 2; ++f) {
        bool ov = (ks0 + 16 > fg_lo[f]) & (ks0 < fg_hi[f]);   // uniform
        bool a = true;
        if (mode == 2) a = ov;
        else if (mode == 1) a = (ks0 < LL) & ((ks0 + 16 > ps) | ov);
        act[f][ns] = a;
        if (a) {
          floatx4 st = __builtin_amdgcn_mfma_f32_16x16x32_bf16(ka[ns], qf[f], zf, 0, 0, 0);
          float e[4];
#pragma unroll
          for (int r = 0; r < 4; ++r) {
            float ev = __builtin_amdgcn_exp2f(st[r]);
            if (mode) {
              int key = ks0 + quad * 4 + r;
              int ing = (key >= glo[f]) & (key < ghi[f]);
              int vis = (mode == 2) ? ing : ((key < LL) & ((key >= ps) | ing));
              ev = vis ? ev : 0.f;
            }
            e[r] = ev;
          }
          lacc[f] += (floatx4){e[0], e[1], e[2], e[3]};
          pt[f][ns] = pack4(e[0], e[1], e[2], e[3]);
        }
      }
    }
#pragma unroll
    for (int f = 0; f < 2; ++f)
#pragma unroll
      for (int db = 0; db < 2; ++db)
#pragma unroll
        for (int ns = 0; ns < 4; ++ns)
          if (mode == 0 || act[f][ns])
            ot[f][db] = __builtin_amdgcn_mfma_f32_16x16x16bf16_1k(va[db][ns], pt[f][ns], ot[f][db], 0, 0, 0);
  };

  // ---- group phase: keys < kb0 visible only inside own group ----
  // parity-split across keyhalf waves
  if (row0 < ps) {
    int rmaxd = row0 + 31;
    if (rmaxd >= ps) rmaxd = ps - 1;
    int c0 = (row0 / sp2) * sp2;
    int c1 = (rmaxd / sp2) * sp2 + sp2;
    if (c1 > ps) c1 = ps;
    int g_t0 = c0 >> 6;
    int g_end = (c1 + 63) >> 6;
    if (g_end > t0) g_end = t0;
    for (int jb = g_t0 + keyhalf; jb < g_end; jb += 2)
      tile_work(jb * 64, 2);
  }

  // ---- band phase: keys [kb0, LPAD), parity-split ----
  for (int kbase = kb0 + keyhalf * 64; kbase < LPAD; kbase += 128) {
    if ((kbase < ps) | (kbase + 64 > LL)) tile_work(kbase, 1);
    else tile_work(kbase, 0);
  }

  // ---- combine partials across keyhalf waves via LDS ----
  if (keyhalf == 1) {
    float* dst = &comb[rowhalf][lane][0];
    *(floatx4*)(dst + 0)  = ot[0][0];
    *(floatx4*)(dst + 4)  = ot[0][1];
    *(floatx4*)(dst + 8)  = ot[1][0];
    *(floatx4*)(dst + 12) = ot[1][1];
    *(floatx4*)(dst + 16) = lacc[0];
    *(floatx4*)(dst + 20) = lacc[1];
  }
  __syncthreads();
  if (keyhalf == 1) return;

  {
    const float* src = &comb[rowhalf][lane][0];
    ot[0][0] += *(const floatx4*)(src + 0);
    ot[0][1] += *(const floatx4*)(src + 4);
    ot[1][0] += *(const floatx4*)(src + 8);
    ot[1][1] += *(const floatx4*)(src + 12);
    lacc[0]  += *(const floatx4*)(src + 16);
    lacc[1]  += *(const floatx4*)(src + 20);
  }

  float li[2];
#pragma unroll
  for (int f = 0; f < 2; ++f) {
    li[f] = (lacc[f][0] + lacc[f][1]) + (lacc[f][2] + lacc[f][3]);
    li[f] += __shfl_xor(li[f], 16);
    li[f] += __shfl_xor(li[f], 32);
  }

  int b = bh >> 3, h = bh & 7;
#pragma unroll
  for (int f = 0; f < 2; ++f) {
    int row = row0 + f * 16 + l15;
    if (row >= LL) continue;
    float inv = 1.f / li[f];
    size_t base = ((size_t)b * LL + row) * EE + h * DD;
#pragma unroll
    for (int db = 0; db < 2; ++db) {
      short4 o;
      o.x = f2bf(ot[f][db][0] * inv);
      o.y = f2bf(ot[f][db][1] * inv);
      o.z = f2bf(ot[f][db][2] * inv);
      o.w = f2bf(ot[f][db][3] * inv);
      *(short4*)(ctx + base + db * 16 + quad * 4) = o;
    }
  }
}

// ---------------- Kernel C: out proj + residual + LayerNorm ---------------
#define OXS 260
__global__ __launch_bounds__(256) void outln_kernel(
    const short* __restrict__ ctx, const short* __restrict__ ow,
    const float* __restrict__ ob, const float* __restrict__ x,
    const float* __restrict__ lg, const float* __restrict__ lb,
    float* __restrict__ out) {
  __shared__ float xs[16 * OXS];        // residual x tile (coalesced staging)
  __shared__ float red[4][16][2];
  int mtile = blockIdx.x;               // 0..949, 16 rows each (exact)
  int wv = threadIdx.x >> 6, lane = threadIdx.x & 63;
  int l15 = lane & 15, quad = lane >> 4;
  int rowbase = mtile * 16;

  float4 xv[4];
#pragma unroll
  for (int i = 0; i < 4; ++i) {
    int row = (threadIdx.x >> 6) + i * 4;
    int col = (threadIdx.x & 63) * 4;
    xv[i] = *(const float4*)(x + (size_t)(rowbase + row) * EE + col);
  }
  const short* crow = ctx + (size_t)(rowbase + l15) * EE;
  bf16x8 ca[8];
#pragma unroll
  for (int ks = 0; ks < 8; ++ks)
    ca[ks] = *(const bf16x8*)(crow + ks * 32 + quad * 8);
  bf16x8 wr[8][4];
#pragma unroll
  for (int ks = 0; ks < 8; ++ks)
#pragma unroll
    for (int ns = 0; ns < 4; ++ns) {
      int frow = wv * 64 + ns * 16 + l15;
      wr[ks][ns] = *(const bf16x8*)(ow + (size_t)frow * EE + ks * 32 + quad * 8);
    }
  asm volatile("" ::: "memory");

#pragma unroll
  for (int i = 0; i < 4; ++i) {
    int row = (threadIdx.x >> 6) + i * 4;
    int col = (threadIdx.x & 63) * 4;
    *(float4*)&xs[row * OXS + col] = xv[i];
  }
  __syncthreads();

  floatx4 acc[4];
#pragma unroll
  for (int i = 0; i < 4; ++i) acc[i] = (floatx4){0.f, 0.f, 0.f, 0.f};
#pragma unroll
  for (int ks = 0; ks < 8; ++ks)
#pragma unroll
    for (int ns = 0; ns < 4; ++ns)
      acc[ns] = __builtin_amdgcn_mfma_f32_16x16x32_bf16(ca[ks], wr[ks][ns], acc[ns], 0, 0, 0);

  float obv[4], lgv[4], lbv[4];
#pragma unroll
  for (int ns = 0; ns < 4; ++ns) {
    int c = wv * 64 + ns * 16 + l15;
    obv[ns] = ob[c]; lgv[ns] = lg[c]; lbv[ns] = lb[c];
  }

  float y[4][4];                         // [ns][r]
  float s1[4] = {0.f, 0.f, 0.f, 0.f}, s2[4] = {0.f, 0.f, 0.f, 0.f};
#pragma unroll
  for (int r = 0; r < 4; ++r) {
    int rr = quad * 4 + r;
#pragma unroll
    for (int ns = 0; ns < 4; ++ns) {
      int c = wv * 64 + ns * 16 + l15;
      float yy = acc[ns][r] + obv[ns] + xs[rr * OXS + c];
      y[ns][r] = yy;
      s1[r] += yy;
      s2[r] += yy * yy;
    }
  }
#pragma unroll
  for (int r = 0; r < 4; ++r) {
#pragma unroll
    for (int off = 1; off < 16; off <<= 1) {
      s1[r] += __shfl_xor(s1[r], off, 16);
      s2[r] += __shfl_xor(s2[r], off, 16);
    }
  }
  if (l15 == 0) {
#pragma unroll
    for (int r = 0; r < 4; ++r) {
      red[wv][quad * 4 + r][0] = s1[r];
      red[wv][quad * 4 + r][1] = s2[r];
    }
  }
  __syncthreads();
#pragma unroll
  for (int r = 0; r < 4; ++r) {
    int rr = quad * 4 + r;
    float t1 = 0.f, t2 = 0.f;
#pragma unroll
    for (int w2 = 0; w2 < 4; ++w2) { t1 += red[w2][rr][0]; t2 += red[w2][rr][1]; }
    float mu = t1 * (1.f / 256.f);
    float var = t2 * (1.f / 256.f) - mu * mu;
    float rs = rsqrtf(var + 1e-5f);
    int tok = rowbase + rr;
#pragma unroll
    for (int ns = 0; ns < 4; ++ns) {
      int c = wv * 64 + ns * 16 + l15;
      out[(size_t)tok * EE + c] = (y[ns][r] - mu) * rs * lgv[ns] + lbv[ns];
    }
  }
}

extern "C" void kernel_launch(void* const* d_in, const int* in_sizes, int n_in,
                              void* d_out, int out_size, void* d_ws, size_t ws_size,
                              hipStream_t stream) {
  const float* x  = (const float*)d_in[0];
  const float* w  = (const float*)d_in[1];
  const float* wb = (const float*)d_in[2];
  const float* ow = (const float*)d_in[3];
  const float* ob = (const float*)d_in[4];
  const float* lg = (const float*)d_in[5];
  const float* lb = (const float*)d_in[6];
  const int* ps = (const int*)d_in[8];   // pad_size
  const int* sp = (const int*)d_in[9];   // single_pad

  short* wbb = (short*)d_ws;                       // 768*256 bf16
  short* owb = wbb + (size_t)768 * EE;             // 256*256 bf16
  short* qw  = owb + (size_t)256 * EE;             // 64*1920*32 bf16 (pre-scaled)
  short* kw  = qw + (size_t)64 * LPAD * DD;
  short* v4w = kw + (size_t)64 * LPAD * DD;        // fragment-layout V
  // xbf (15264*264 shorts, 8.06 MB) and ctx (15200*256 shorts, 7.78 MB)
  // have disjoint lifetimes -> alias them in the same workspace region.
  short* xbf = v4w + (size_t)64 * BHST;
  short* ctx = xbf;

  cvt_kernel<<<CVT_TOT / 256, 256, 0, stream>>>(w, ow, x, wbb, owb, xbf);
  qkv_kernel<<<240 * 6, 256, 0, stream>>>(xbf, wbb, wb, qw, kw, v4w);
  attn_kernel<<<30 * 64, 256, 0, stream>>>(qw, kw, v4w, ctx, ps, sp);
  outln_kernel<<<950, 256, 0, stream>>>(ctx, owb, ob, x, lg, lb, (float*)d_out);
}

// Round 11
// 165.799 us; speedup vs baseline: 1.8394x; 1.8394x over previous
//
#include <hip/hip_runtime.h>
#include <math.h>

#define BB 8
#define LL 1900
#define LPAD 1920
#define EE 256
#define HH 8
#define DD 32
#define MTOK (BB*LL)              // 15200
#define SCALE 0.17677669529663687f
#define LOG2E 1.4426950408889634f
#define NKB 120                   // keyblocks of 16 per (b,h)
#define BHST (NKB*2*256)          // 61440 shorts per (b,h) in v4

typedef __attribute__((ext_vector_type(8))) short bf16x8;
typedef __attribute__((ext_vector_type(4))) short bf16x4;
typedef __attribute__((ext_vector_type(4))) float floatx4;
typedef __attribute__((ext_vector_type(2))) unsigned uintx2;

__device__ inline short f2bf(float f) {
  unsigned u = __builtin_bit_cast(unsigned, f);
  u += 0x7FFF + ((u >> 16) & 1);
  return (short)(u >> 16);
}

// pack 4 fp32 -> 4 bf16 (truncate) via v_perm_b32
__device__ inline bf16x4 pack4(float s0, float s1, float s2, float s3) {
  uintx2 u;
  u.x = __builtin_amdgcn_perm(__builtin_bit_cast(unsigned, s1),
                              __builtin_bit_cast(unsigned, s0), 0x07060302u);
  u.y = __builtin_amdgcn_perm(__builtin_bit_cast(unsigned, s3),
                              __builtin_bit_cast(unsigned, s2), 0x07060302u);
  return __builtin_bit_cast(bf16x4, u);
}

// async global->LDS DMA, 16 B per lane; lds base must be wave-uniform
__device__ inline void load_lds16(const void* g, void* l) {
  __builtin_amdgcn_global_load_lds(
      (const __attribute__((address_space(1))) unsigned*)g,
      (__attribute__((address_space(3))) unsigned*)l, 16, 0, 0);
}

// ---------------- Kernel 0: fp32 -> bf16 for in_proj_w, out_w, AND x ------
// x lands padded: [XROWS][XSTR] bf16, XSTR=264 shorts (528 B = 33*16 B:
// 16B-multiple for linear DMA; 132 dw == 4 (mod 32) -> 2-way-free banks
// for the stride-XSTR A-fragment reads). Rows >= MTOK zero-filled.
#define CVT_W4  49152             // 196608/4
#define CVT_OW4 16384             // 65536/4
#define XROWS 15264
#define XSTR  264
#define CVT_X4 (XROWS*64)         // 976896
#define CVT_TOT (CVT_W4 + CVT_OW4 + CVT_X4)   // 1042432 = 4072*256
__global__ __launch_bounds__(256) void cvt_kernel(
    const float* __restrict__ w, const float* __restrict__ ow,
    const float* __restrict__ x,
    short* __restrict__ wb, short* __restrict__ owb, short* __restrict__ xb) {
  int i = blockIdx.x * 256 + threadIdx.x;
  if (i < CVT_W4 + CVT_OW4) {
    const float* src; short* dst; int off;
    if (i < CVT_W4) { src = w; dst = wb; off = i; }
    else { src = ow; dst = owb; off = i - CVT_W4; }
    float4 v = *(const float4*)(src + (size_t)off * 4);
    short4 o;
    o.x = f2bf(v.x); o.y = f2bf(v.y); o.z = f2bf(v.z); o.w = f2bf(v.w);
    *(short4*)(dst + (size_t)off * 4) = o;
  } else {
    int j = i - (CVT_W4 + CVT_OW4);
    int row = j >> 6, seg = j & 63;
    short4 o; o.x = 0; o.y = 0; o.z = 0; o.w = 0;
    if (row < MTOK) {
      float4 v = *(const float4*)(x + (size_t)row * EE + seg * 4);
      o.x = f2bf(v.x); o.y = f2bf(v.y); o.z = f2bf(v.z); o.w = f2bf(v.w);
    }
    *(short4*)(xb + (size_t)row * XSTR + seg * 4) = o;
  }
}

// ---------------- Kernel A: QKV projection, LDS-shared w, A-in-regs -------
#define XWSH (16*XSTR)            // 4224 shorts per wave x-slice
#define LDS_SH 17280              // 34,560 B: fits x-slices / w-tile / cbuf
__global__ __launch_bounds__(256, 4) void qkv_kernel(
    const short* __restrict__ xbf, const short* __restrict__ w,
    const float* __restrict__ bias, short* __restrict__ q,
    short* __restrict__ k, short* __restrict__ v4) {
  __shared__ short lds[LDS_SH];
  int bid = blockIdx.x;
  int mtile = bid % 240, npair = bid / 240;   // npair 0..5 -> ntiles 2p,2p+1
  if (mtile >= 238) return;
  int wv = threadIdx.x >> 6, lane = threadIdx.x & 63;
  int l15 = lane & 15, quad = lane >> 4;

  // ---- DMA phase: 16 bf16 rows = 8448 B/wave, 9 x 1 KB linear chunks ----
  const short* gsrc = xbf + (size_t)(mtile * 64 + wv * 16) * XSTR;
  char* xw = (char*)&lds[wv * XWSH];
#pragma unroll
  for (int i = 0; i < 9; ++i)
    load_lds16((const char*)gsrc + i * 1024 + lane * 16, xw + i * 1024);
  asm volatile("s_waitcnt vmcnt(0)" ::: "memory");

  // ---- A-fragments to registers (wave-private slice; no barrier needed) --
  bf16x8 af[8];
#pragma unroll
  for (int ks = 0; ks < 8; ++ks)
    af[ks] = *(const bf16x8*)&lds[wv * XWSH + l15 * XSTR + ks * 32 + quad * 8];
  __syncthreads();   // all A-reads done before w-tile overwrites lds

  floatx4 accs[2][4];
#pragma unroll
  for (int s = 0; s < 2; ++s)
#pragma unroll
    for (int i = 0; i < 4; ++i) accs[s][i] = (floatx4){0.f, 0.f, 0.f, 0.f};

#pragma unroll
  for (int s = 0; s < 2; ++s) {
    int ntile = npair * 2 + s;
    // stage 64x256 w-tile -> padded [64][XSTR] (coalesced global reads)
    const short* wsub = w + (size_t)ntile * 64 * EE;
#pragma unroll
    for (int i = 0; i < 8; ++i) {
      int c = threadIdx.x + i * 256;      // 0..2047 16B-chunks
      int row = c >> 5, col = (c & 31) * 8;
      *(bf16x8*)&lds[row * XSTR + col] = *(const bf16x8*)(wsub + row * EE + col);
    }
    __syncthreads();
#pragma unroll
    for (int ks = 0; ks < 8; ++ks)
#pragma unroll
      for (int ns = 0; ns < 4; ++ns) {
        bf16x8 bfr = *(const bf16x8*)&lds[(ns * 16 + l15) * XSTR + ks * 32 + quad * 8];
        accs[s][ns] = __builtin_amdgcn_mfma_f32_16x16x32_bf16(af[ks], bfr, accs[s][ns], 0, 0, 0);
      }
    __syncthreads();   // done reading w-tile before restage / cbuf reuse
  }

  // ---- epilogue per sub-ntile: bias(+scale), LDS transpose, stores ----
  short* cbuf = (short*)lds;               // 64*72 shorts, aliases lds
  int t0tok = mtile * 64;
  int b0 = t0tok / LL;
  bool uni = (b0 == (t0tok + 63) / LL) && (t0tok + 63 < MTOK);

#pragma unroll
  for (int s = 0; s < 2; ++s) {
    int ntile = npair * 2 + s;
    float qs = (ntile < 4) ? (SCALE * LOG2E) : 1.0f;
#pragma unroll
    for (int ns = 0; ns < 4; ++ns) {
      float bv = bias[ntile * 64 + ns * 16 + l15];
#pragma unroll
      for (int r = 0; r < 4; ++r)
        cbuf[(wv * 16 + quad * 4 + r) * 72 + ns * 16 + l15] =
            f2bf((accs[s][ns][r] + bv) * qs);
    }
    __syncthreads();

    int which = ntile >> 2;          // 0=q 1=k 2=v
    int fbase = (ntile & 3) * 64;

    if (which < 2) {
      short* dst0 = which ? k : q;
      int tl = threadIdx.x >> 2, seg = threadIdx.x & 3;
      int tok = t0tok + tl;
      if (tok < MTOK) {
        int b = uni ? b0 : tok / LL;
        int l = tok - b * LL;
        int fl = seg * 16;
        int h = (fbase + fl) >> 5;
        int d = (fbase + fl) & 31;
        size_t base = ((size_t)(b * HH + h) * LPAD + l) * DD + d;
        bf16x8 v0 = *(bf16x8*)(&cbuf[tl * 72 + fl]);
        bf16x8 v1 = *(bf16x8*)(&cbuf[tl * 72 + fl + 8]);
        *(bf16x8*)(dst0 + base) = v0;
        *(bf16x8*)(dst0 + base + 8) = v1;
      }
    } else {
      // V -> fragment layout v4
      int fl = threadIdx.x >> 2, ls = threadIdx.x & 3;
      int h = (fbase + fl) >> 5;
      int d = (fbase + fl) & 31;
      int db = d >> 4, dl = d & 15;
      if (uni) {
        int l0 = t0tok - b0 * LL + ls * 16;   // 4-aligned (1900 % 4 == 0)
        short* Vb = v4 + (size_t)(b0 * HH + h) * BHST;
#pragma unroll
        for (int g4 = 0; g4 < 4; ++g4) {
          int l = l0 + g4 * 4;
          int kb = l >> 4, qd = (l >> 2) & 3; // l&3 == 0
          int tb = ls * 16 + g4 * 4;
          short4 vv;
          vv.x = cbuf[(tb + 0) * 72 + fl];
          vv.y = cbuf[(tb + 1) * 72 + fl];
          vv.z = cbuf[(tb + 2) * 72 + fl];
          vv.w = cbuf[(tb + 3) * 72 + fl];
          *(short4*)(Vb + (size_t)(kb * 2 + db) * 256 + (dl + 16 * qd) * 4) = vv;
        }
      } else {
#pragma unroll
        for (int i = 0; i < 16; ++i) {
          int tl = ls * 16 + i;
          int tok = t0tok + tl;
          if (tok < MTOK) {
            int b = tok / LL;
            int l = tok - b * LL;
            int kb = l >> 4, qd = (l >> 2) & 3, j = l & 3;
            v4[(size_t)(b * HH + h) * BHST + (size_t)(kb * 2 + db) * 256 +
               (dl + 16 * qd) * 4 + j] = cbuf[tl * 72 + fl];
          }
        }
      }
    }
    __syncthreads();   // cbuf free before next sub-ntile overwrites it
  }
}

// ---------------- Kernel B: flash attention, key-split waves --------------
// Scores are exp2'd with NO running max -> partial (ot, li) over disjoint
// key sets combine LINEARLY. 4-wave blocks: wave = (rowhalf, keyhalf);
// each wave covers its 32 rows over every OTHER tile. 7680 waves total
// (7.5/SIMD) vs R9's 3840 -- R9 was wave-starved.
// R10 bug fixed: __launch_bounds__(256,8) capped VGPRs below the live
// state (~60) -> accumulators spilled to scratch (FETCH 213 MB, WRITE
// 398 MB, 186 us). (256,4) gives the allocator 128 VGPRs; grid alone
// provides the occupancy (7.5 blocks/CU).
__global__ __launch_bounds__(256, 4) void attn_kernel(
    const short* __restrict__ q, const short* __restrict__ k,
    const short* __restrict__ v4, short* __restrict__ ctx,
    const int* __restrict__ pad_size_p, const int* __restrict__ single_pad_p) {
  __shared__ float comb[2][64][24];   // 12,288 B (16B-aligned per lane)
  int bid = blockIdx.x;
  int bh = bid & 63, slot2 = bid >> 6;   // bh fastest -> 8 heads/XCD (L2 fit)
  int wv = threadIdx.x >> 6, lane = threadIdx.x & 63;
  int rowhalf = wv & 1, keyhalf = wv >> 1;
  int l15 = lane & 15, quad = lane >> 4;

  int ps = pad_size_p[0];
  int sp2 = 2 * single_pad_p[0];
  int t0 = ps >> 6;                  // 15
  int kb0 = t0 * 64;                 // 960

  const short* Q = q + (size_t)bh * LPAD * DD;
  const short* K = k + (size_t)bh * LPAD * DD;
  const short* V4 = v4 + (size_t)bh * BHST;
  int lane4 = lane * 4;

  int row0 = slot2 * 64 + rowhalf * 32;   // 32 rows per wave-pair

  bf16x8 qf[2];
  qf[0] = *(const bf16x8*)(Q + (size_t)(row0 + l15) * DD + quad * 8);
  qf[1] = *(const bf16x8*)(Q + (size_t)(row0 + 16 + l15) * DD + quad * 8);

  // per-lane group window (for masking)
  int glo[2], ghi[2];
  // per-half uniform group span (for slice skipping)
  int fg_lo[2], fg_hi[2];
#pragma unroll
  for (int f = 0; f < 2; ++f) {
    int row = row0 + f * 16 + l15;
    int g = row / sp2;
    int lo = g * sp2, hi = lo + sp2;
    if (row >= ps) { lo = 0; hi = 0; }
    glo[f] = lo; ghi[f] = hi;
    int first = row0 + f * 16, last = first + 15;
    if (first >= ps) { fg_lo[f] = 0; fg_hi[f] = 0; }
    else { fg_lo[f] = (first / sp2) * sp2; fg_hi[f] = (last / sp2) * sp2 + sp2; }
  }

  floatx4 lacc[2];
  lacc[0] = (floatx4){0.f, 0.f, 0.f, 0.f};
  lacc[1] = (floatx4){0.f, 0.f, 0.f, 0.f};
  floatx4 ot[2][2];
#pragma unroll
  for (int f = 0; f < 2; ++f)
#pragma unroll
    for (int db = 0; db < 2; ++db) ot[f][db] = (floatx4){0.f, 0.f, 0.f, 0.f};
  const floatx4 zf = (floatx4){0.f, 0.f, 0.f, 0.f};

  // one 64-key tile. mode: 0 = band-clean, 1 = band edge (ps/LL), 2 = group
  auto tile_work = [&](int kbase, int mode) {
    const short* vp = V4 + (size_t)(kbase >> 4) * 512;        // tile base
    const short* kp = K + (size_t)kbase * DD + l15 * DD + quad * 8;
    bf16x8 ka[4];
    bf16x4 va[2][4];
#pragma unroll
    for (int ns = 0; ns < 4; ++ns)
      ka[ns] = *(const bf16x8*)(kp + ns * 512);   // 16 keys * 32 shorts
#pragma unroll
    for (int db = 0; db < 2; ++db)
#pragma unroll
      for (int ns = 0; ns < 4; ++ns)
        va[db][ns] = *(const bf16x4*)(vp + (ns * 2 + db) * 256 + lane4);

    bool act[2][4];
    bf16x4 pt[2][4];
#pragma unroll
    for (int ns = 0; ns < 4; ++ns) {
      int ks0 = kbase + ns * 16;
#pragma unroll
      for (int f = 0; f < 2; ++f) {
        bool ov = (ks0 + 16 > fg_lo[f]) & (ks0 < fg_hi[f]);   // uniform
        bool a = true;
        if (mode == 2) a = ov;
        else if (mode == 1) a = (ks0 < LL) & ((ks0 + 16 > ps) | ov);
        act[f][ns] = a;
        if (a) {
          floatx4 st = __builtin_amdgcn_mfma_f32_16x16x32_bf16(ka[ns], qf[f], zf, 0, 0, 0);
          float e[4];
#pragma unroll
          for (int r = 0; r < 4; ++r) {
            float ev = __builtin_amdgcn_exp2f(st[r]);
            if (mode) {
              int key = ks0 + quad * 4 + r;
              int ing = (key >= glo[f]) & (key < ghi[f]);
              int vis = (mode == 2) ? ing : ((key < LL) & ((key >= ps) | ing));
              ev = vis ? ev : 0.f;
            }
            e[r] = ev;
          }
          lacc[f] += (floatx4){e[0], e[1], e[2], e[3]};
          pt[f][ns] = pack4(e[0], e[1], e[2], e[3]);
        }
      }
    }
#pragma unroll
    for (int f = 0; f < 2; ++f)
#pragma unroll
      for (int db = 0; db < 2; ++db)
#pragma unroll
        for (int ns = 0; ns < 4; ++ns)
          if (mode == 0 || act[f][ns])
            ot[f][db] = __builtin_amdgcn_mfma_f32_16x16x16bf16_1k(va[db][ns], pt[f][ns], ot[f][db], 0, 0, 0);
  };

  // ---- group phase: keys < kb0 visible only inside own group ----
  // parity-split across keyhalf waves
  if (row0 < ps) {
    int rmaxd = row0 + 31;
    if (rmaxd >= ps) rmaxd = ps - 1;
    int c0 = (row0 / sp2) * sp2;
    int c1 = (rmaxd / sp2) * sp2 + sp2;
    if (c1 > ps) c1 = ps;
    int g_t0 = c0 >> 6;
    int g_end = (c1 + 63) >> 6;
    if (g_end > t0) g_end = t0;
    for (int jb = g_t0 + keyhalf; jb < g_end; jb += 2)
      tile_work(jb * 64, 2);
  }

  // ---- band phase: keys [kb0, LPAD), parity-split ----
  for (int kbase = kb0 + keyhalf * 64; kbase < LPAD; kbase += 128) {
    if ((kbase < ps) | (kbase + 64 > LL)) tile_work(kbase, 1);
    else tile_work(kbase, 0);
  }

  // ---- combine partials across keyhalf waves via LDS ----
  if (keyhalf == 1) {
    float* dst = &comb[rowhalf][lane][0];
    *(floatx4*)(dst + 0)  = ot[0][0];
    *(floatx4*)(dst + 4)  = ot[0][1];
    *(floatx4*)(dst + 8)  = ot[1][0];
    *(floatx4*)(dst + 12) = ot[1][1];
    *(floatx4*)(dst + 16) = lacc[0];
    *(floatx4*)(dst + 20) = lacc[1];
  }
  __syncthreads();
  if (keyhalf == 1) return;

  {
    const float* src = &comb[rowhalf][lane][0];
    ot[0][0] += *(const floatx4*)(src + 0);
    ot[0][1] += *(const floatx4*)(src + 4);
    ot[1][0] += *(const floatx4*)(src + 8);
    ot[1][1] += *(const floatx4*)(src + 12);
    lacc[0]  += *(const floatx4*)(src + 16);
    lacc[1]  += *(const floatx4*)(src + 20);
  }

  float li[2];
#pragma unroll
  for (int f = 0; f < 2; ++f) {
    li[f] = (lacc[f][0] + lacc[f][1]) + (lacc[f][2] + lacc[f][3]);
    li[f] += __shfl_xor(li[f], 16);
    li[f] += __shfl_xor(li[f], 32);
  }

  int b = bh >> 3, h = bh & 7;
#pragma unroll
  for (int f = 0; f < 2; ++f) {
    int row = row0 + f * 16 + l15;
    if (row >= LL) continue;
    float inv = 1.f / li[f];
    size_t base = ((size_t)b * LL + row) * EE + h * DD;
#pragma unroll
    for (int db = 0; db < 2; ++db) {
      short4 o;
      o.x = f2bf(ot[f][db][0] * inv);
      o.y = f2bf(ot[f][db][1] * inv);
      o.z = f2bf(ot[f][db][2] * inv);
      o.w = f2bf(ot[f][db][3] * inv);
      *(short4*)(ctx + base + db * 16 + quad * 4) = o;
    }
  }
}

// ---------------- Kernel C: out proj + residual + LayerNorm ---------------
#define OXS 260
__global__ __launch_bounds__(256) void outln_kernel(
    const short* __restrict__ ctx, const short* __restrict__ ow,
    const float* __restrict__ ob, const float* __restrict__ x,
    const float* __restrict__ lg, const float* __restrict__ lb,
    float* __restrict__ out) {
  __shared__ float xs[16 * OXS];        // residual x tile (coalesced staging)
  __shared__ float red[4][16][2];
  int mtile = blockIdx.x;               // 0..949, 16 rows each (exact)
  int wv = threadIdx.x >> 6, lane = threadIdx.x & 63;
  int l15 = lane & 15, quad = lane >> 4;
  int rowbase = mtile * 16;

  float4 xv[4];
#pragma unroll
  for (int i = 0; i < 4; ++i) {
    int row = (threadIdx.x >> 6) + i * 4;
    int col = (threadIdx.x & 63) * 4;
    xv[i] = *(const float4*)(x + (size_t)(rowbase + row) * EE + col);
  }
  const short* crow = ctx + (size_t)(rowbase + l15) * EE;
  bf16x8 ca[8];
#pragma unroll
  for (int ks = 0; ks < 8; ++ks)
    ca[ks] = *(const bf16x8*)(crow + ks * 32 + quad * 8);
  bf16x8 wr[8][4];
#pragma unroll
  for (int ks = 0; ks < 8; ++ks)
#pragma unroll
    for (int ns = 0; ns < 4; ++ns) {
      int frow = wv * 64 + ns * 16 + l15;
      wr[ks][ns] = *(const bf16x8*)(ow + (size_t)frow * EE + ks * 32 + quad * 8);
    }
  asm volatile("" ::: "memory");

#pragma unroll
  for (int i = 0; i < 4; ++i) {
    int row = (threadIdx.x >> 6) + i * 4;
    int col = (threadIdx.x & 63) * 4;
    *(float4*)&xs[row * OXS + col] = xv[i];
  }
  __syncthreads();

  floatx4 acc[4];
#pragma unroll
  for (int i = 0; i < 4; ++i) acc[i] = (floatx4){0.f, 0.f, 0.f, 0.f};
#pragma unroll
  for (int ks = 0; ks < 8; ++ks)
#pragma unroll
    for (int ns = 0; ns < 4; ++ns)
      acc[ns] = __builtin_amdgcn_mfma_f32_16x16x32_bf16(ca[ks], wr[ks][ns], acc[ns], 0, 0, 0);

  float obv[4], lgv[4], lbv[4];
#pragma unroll
  for (int ns = 0; ns < 4; ++ns) {
    int c = wv * 64 + ns * 16 + l15;
    obv[ns] = ob[c]; lgv[ns] = lg[c]; lbv[ns] = lb[c];
  }

  float y[4][4];                         // [ns][r]
  float s1[4] = {0.f, 0.f, 0.f, 0.f}, s2[4] = {0.f, 0.f, 0.f, 0.f};
#pragma unroll
  for (int r = 0; r < 4; ++r) {
    int rr = quad * 4 + r;
#pragma unroll
    for (int ns = 0; ns < 4; ++ns) {
      int c = wv * 64 + ns * 16 + l15;
      float yy = acc[ns][r] + obv[ns] + xs[rr * OXS + c];
      y[ns][r] = yy;
      s1[r] += yy;
      s2[r] += yy * yy;
    }
  }
#pragma unroll
  for (int r = 0; r < 4; ++r) {
#pragma unroll
    for (int off = 1; off < 16; off <<= 1) {
      s1[r] += __shfl_xor(s1[r], off, 16);
      s2[r] += __shfl_xor(s2[r], off, 16);
    }
  }
  if (l15 == 0) {
#pragma unroll
    for (int r = 0; r < 4; ++r) {
      red[wv][quad * 4 + r][0] = s1[r];
      red[wv][quad * 4 + r][1] = s2[r];
    }
  }
  __syncthreads();
#pragma unroll
  for (int r = 0; r < 4; ++r) {
    int rr = quad * 4 + r;
    float t1 = 0.f, t2 = 0.f;
#pragma unroll
    for (int w2 = 0; w2 < 4; ++w2) { t1 += red[w2][rr][0]; t2 += red[w2][rr][1]; }
    float mu = t1 * (1.f / 256.f);
    float var = t2 * (1.f / 256.f) - mu * mu;
    float rs = rsqrtf(var + 1e-5f);
    int tok = rowbase + rr;
#pragma unroll
    for (int ns = 0; ns < 4; ++ns) {
      int c = wv * 64 + ns * 16 + l15;
      out[(size_t)tok * EE + c] = (y[ns][r] - mu) * rs * lgv[ns] + lbv[ns];
    }
  }
}

extern "C" void kernel_launch(void* const* d_in, const int* in_sizes, int n_in,
                              void* d_out, int out_size, void* d_ws, size_t ws_size,
                              hipStream_t stream) {
  const float* x  = (const float*)d_in[0];
  const float* w  = (const float*)d_in[1];
  const float* wb = (const float*)d_in[2];
  const float* ow = (const float*)d_in[3];
  const float* ob = (const float*)d_in[4];
  const float* lg = (const float*)d_in[5];
  const float* lb = (const float*)d_in[6];
  const int* ps = (const int*)d_in[8];   // pad_size
  const int* sp = (const int*)d_in[9];   // single_pad

  short* wbb = (short*)d_ws;                       // 768*256 bf16
  short* owb = wbb + (size_t)768 * EE;             // 256*256 bf16
  short* qw  = owb + (size_t)256 * EE;             // 64*1920*32 bf16 (pre-scaled)
  short* kw  = qw + (size_t)64 * LPAD * DD;
  short* v4w = kw + (size_t)64 * LPAD * DD;        // fragment-layout V
  // xbf (15264*264 shorts, 8.06 MB) and ctx (15200*256 shorts, 7.78 MB)
  // have disjoint lifetimes -> alias them in the same workspace region.
  short* xbf = v4w + (size_t)64 * BHST;
  short* ctx = xbf;

  cvt_kernel<<<CVT_TOT / 256, 256, 0, stream>>>(w, ow, x, wbb, owb, xbf);
  qkv_kernel<<<240 * 6, 256, 0, stream>>>(xbf, wbb, wb, qw, kw, v4w);
  attn_kernel<<<30 * 64, 256, 0, stream>>>(qw, kw, v4w, ctx, ps, sp);
  outln_kernel<<<950, 256, 0, stream>>>(ctx, owb, ob, x, lg, lb, (float*)d_out);
}

// Round 12
// 165.247 us; speedup vs baseline: 1.8456x; 1.0033x over previous
//
#include <hip/hip_runtime.h>
#include <math.h>

#define BB 8
#define LL 1900
#define LPAD 1920
#define EE 256
#define HH 8
#define DD 32
#define MTOK (BB*LL)              // 15200
#define SCALE 0.17677669529663687f
#define LOG2E 1.4426950408889634f
#define NKB 120                   // keyblocks of 16 per (b,h)
#define BHST (NKB*2*256)          // 61440 shorts per (b,h) in v4

typedef __attribute__((ext_vector_type(8))) short bf16x8;
typedef __attribute__((ext_vector_type(4))) short bf16x4;
typedef __attribute__((ext_vector_type(4))) float floatx4;
typedef __attribute__((ext_vector_type(2))) unsigned uintx2;

__device__ inline short f2bf(float f) {
  unsigned u = __builtin_bit_cast(unsigned, f);
  u += 0x7FFF + ((u >> 16) & 1);
  return (short)(u >> 16);
}

// pack 4 fp32 -> 4 bf16 (truncate) via v_perm_b32
__device__ inline bf16x4 pack4(float s0, float s1, float s2, float s3) {
  uintx2 u;
  u.x = __builtin_amdgcn_perm(__builtin_bit_cast(unsigned, s1),
                              __builtin_bit_cast(unsigned, s0), 0x07060302u);
  u.y = __builtin_amdgcn_perm(__builtin_bit_cast(unsigned, s3),
                              __builtin_bit_cast(unsigned, s2), 0x07060302u);
  return __builtin_bit_cast(bf16x4, u);
}

// async global->LDS DMA, 16 B per lane; lds base must be wave-uniform
__device__ inline void load_lds16(const void* g, void* l) {
  __builtin_amdgcn_global_load_lds(
      (const __attribute__((address_space(1))) unsigned*)g,
      (__attribute__((address_space(3))) unsigned*)l, 16, 0, 0);
}

// ---------------- Kernel 0: fp32 -> bf16 for in_proj_w, out_w, AND x ------
// x lands padded: [XROWS][XSTR] bf16, XSTR=264 shorts (528 B = 33*16 B:
// 16B-multiple for linear DMA; 132 dw == 4 (mod 32) -> 2-way-free banks
// for the stride-XSTR A-fragment reads). Rows >= MTOK zero-filled.
#define CVT_W4  49152             // 196608/4
#define CVT_OW4 16384             // 65536/4
#define XROWS 15264
#define XSTR  264
#define CVT_X4 (XROWS*64)         // 976896
#define CVT_TOT (CVT_W4 + CVT_OW4 + CVT_X4)   // 1042432 = 4072*256
__global__ __launch_bounds__(256) void cvt_kernel(
    const float* __restrict__ w, const float* __restrict__ ow,
    const float* __restrict__ x,
    short* __restrict__ wb, short* __restrict__ owb, short* __restrict__ xb) {
  int i = blockIdx.x * 256 + threadIdx.x;
  if (i < CVT_W4 + CVT_OW4) {
    const float* src; short* dst; int off;
    if (i < CVT_W4) { src = w; dst = wb; off = i; }
    else { src = ow; dst = owb; off = i - CVT_W4; }
    float4 v = *(const float4*)(src + (size_t)off * 4);
    short4 o;
    o.x = f2bf(v.x); o.y = f2bf(v.y); o.z = f2bf(v.z); o.w = f2bf(v.w);
    *(short4*)(dst + (size_t)off * 4) = o;
  } else {
    int j = i - (CVT_W4 + CVT_OW4);
    int row = j >> 6, seg = j & 63;
    short4 o; o.x = 0; o.y = 0; o.z = 0; o.w = 0;
    if (row < MTOK) {
      float4 v = *(const float4*)(x + (size_t)row * EE + seg * 4);
      o.x = f2bf(v.x); o.y = f2bf(v.y); o.z = f2bf(v.z); o.w = f2bf(v.w);
    }
    *(short4*)(xb + (size_t)row * XSTR + seg * 4) = o;
  }
}

// ---------------- Kernel A: QKV projection, LDS-shared w, A-in-regs -------
#define XWSH (16*XSTR)            // 4224 shorts per wave x-slice
#define LDS_SH 17280              // 34,560 B: fits x-slices / w-tile / cbuf
__global__ __launch_bounds__(256, 4) void qkv_kernel(
    const short* __restrict__ xbf, const short* __restrict__ w,
    const float* __restrict__ bias, short* __restrict__ q,
    short* __restrict__ k, short* __restrict__ v4) {
  __shared__ short lds[LDS_SH];
  int bid = blockIdx.x;
  int mtile = bid % 240, npair = bid / 240;   // npair 0..5 -> ntiles 2p,2p+1
  if (mtile >= 238) return;
  int wv = threadIdx.x >> 6, lane = threadIdx.x & 63;
  int l15 = lane & 15, quad = lane >> 4;

  // ---- DMA phase: 16 bf16 rows = 8448 B/wave, 9 x 1 KB linear chunks ----
  const short* gsrc = xbf + (size_t)(mtile * 64 + wv * 16) * XSTR;
  char* xw = (char*)&lds[wv * XWSH];
#pragma unroll
  for (int i = 0; i < 9; ++i)
    load_lds16((const char*)gsrc + i * 1024 + lane * 16, xw + i * 1024);
  asm volatile("s_waitcnt vmcnt(0)" ::: "memory");

  // ---- A-fragments to registers (wave-private slice; no barrier needed) --
  bf16x8 af[8];
#pragma unroll
  for (int ks = 0; ks < 8; ++ks)
    af[ks] = *(const bf16x8*)&lds[wv * XWSH + l15 * XSTR + ks * 32 + quad * 8];
  __syncthreads();   // all A-reads done before w-tile overwrites lds

  floatx4 accs[2][4];
#pragma unroll
  for (int s = 0; s < 2; ++s)
#pragma unroll
    for (int i = 0; i < 4; ++i) accs[s][i] = (floatx4){0.f, 0.f, 0.f, 0.f};

#pragma unroll
  for (int s = 0; s < 2; ++s) {
    int ntile = npair * 2 + s;
    // stage 64x256 w-tile -> padded [64][XSTR] (coalesced global reads)
    const short* wsub = w + (size_t)ntile * 64 * EE;
#pragma unroll
    for (int i = 0; i < 8; ++i) {
      int c = threadIdx.x + i * 256;      // 0..2047 16B-chunks
      int row = c >> 5, col = (c & 31) * 8;
      *(bf16x8*)&lds[row * XSTR + col] = *(const bf16x8*)(wsub + row * EE + col);
    }
    __syncthreads();
#pragma unroll
    for (int ks = 0; ks < 8; ++ks)
#pragma unroll
      for (int ns = 0; ns < 4; ++ns) {
        bf16x8 bfr = *(const bf16x8*)&lds[(ns * 16 + l15) * XSTR + ks * 32 + quad * 8];
        accs[s][ns] = __builtin_amdgcn_mfma_f32_16x16x32_bf16(af[ks], bfr, accs[s][ns], 0, 0, 0);
      }
    __syncthreads();   // done reading w-tile before restage / cbuf reuse
  }

  // ---- epilogue per sub-ntile: bias(+scale), LDS transpose, stores ----
  short* cbuf = (short*)lds;               // 64*72 shorts, aliases lds
  int t0tok = mtile * 64;
  int b0 = t0tok / LL;
  bool uni = (b0 == (t0tok + 63) / LL) && (t0tok + 63 < MTOK);

#pragma unroll
  for (int s = 0; s < 2; ++s) {
    int ntile = npair * 2 + s;
    float qs = (ntile < 4) ? (SCALE * LOG2E) : 1.0f;
#pragma unroll
    for (int ns = 0; ns < 4; ++ns) {
      float bv = bias[ntile * 64 + ns * 16 + l15];
#pragma unroll
      for (int r = 0; r < 4; ++r)
        cbuf[(wv * 16 + quad * 4 + r) * 72 + ns * 16 + l15] =
            f2bf((accs[s][ns][r] + bv) * qs);
    }
    __syncthreads();

    int which = ntile >> 2;          // 0=q 1=k 2=v
    int fbase = (ntile & 3) * 64;

    if (which < 2) {
      short* dst0 = which ? k : q;
      int tl = threadIdx.x >> 2, seg = threadIdx.x & 3;
      int tok = t0tok + tl;
      if (tok < MTOK) {
        int b = uni ? b0 : tok / LL;
        int l = tok - b * LL;
        int fl = seg * 16;
        int h = (fbase + fl) >> 5;
        int d = (fbase + fl) & 31;
        size_t base = ((size_t)(b * HH + h) * LPAD + l) * DD + d;
        bf16x8 v0 = *(bf16x8*)(&cbuf[tl * 72 + fl]);
        bf16x8 v1 = *(bf16x8*)(&cbuf[tl * 72 + fl + 8]);
        *(bf16x8*)(dst0 + base) = v0;
        *(bf16x8*)(dst0 + base + 8) = v1;
      }
    } else {
      // V -> fragment layout v4
      int fl = threadIdx.x >> 2, ls = threadIdx.x & 3;
      int h = (fbase + fl) >> 5;
      int d = (fbase + fl) & 31;
      int db = d >> 4, dl = d & 15;
      if (uni) {
        int l0 = t0tok - b0 * LL + ls * 16;   // 4-aligned (1900 % 4 == 0)
        short* Vb = v4 + (size_t)(b0 * HH + h) * BHST;
#pragma unroll
        for (int g4 = 0; g4 < 4; ++g4) {
          int l = l0 + g4 * 4;
          int kb = l >> 4, qd = (l >> 2) & 3; // l&3 == 0
          int tb = ls * 16 + g4 * 4;
          short4 vv;
          vv.x = cbuf[(tb + 0) * 72 + fl];
          vv.y = cbuf[(tb + 1) * 72 + fl];
          vv.z = cbuf[(tb + 2) * 72 + fl];
          vv.w = cbuf[(tb + 3) * 72 + fl];
          *(short4*)(Vb + (size_t)(kb * 2 + db) * 256 + (dl + 16 * qd) * 4) = vv;
        }
      } else {
#pragma unroll
        for (int i = 0; i < 16; ++i) {
          int tl = ls * 16 + i;
          int tok = t0tok + tl;
          if (tok < MTOK) {
            int b = tok / LL;
            int l = tok - b * LL;
            int kb = l >> 4, qd = (l >> 2) & 3, j = l & 3;
            v4[(size_t)(b * HH + h) * BHST + (size_t)(kb * 2 + db) * 256 +
               (dl + 16 * qd) * 4 + j] = cbuf[tl * 72 + fl];
          }
        }
      }
    }
    __syncthreads();   // cbuf free before next sub-ntile overwrites it
  }
}

// ---------------- Kernel B: flash attention, key-split + MFMA-li ----------
// Key-split waves as R11. NEW: the softmax denominator is computed on the
// MATRIX pipe instead of VALU -- lsum[f] accumulates mfma(ones, pt, lsum):
// with an all-ones A-fragment, C[i][j] = sum_k P[k][j], so the full 16-key
// slice sum (across quads) lands in lsum[f][0] with zero VALU adds and no
// final shuffle reduce. Removes 32 v_add_f32/tile + 4 shuffles from the
// critical VALU path (VALU was the busiest pipe at 40%; matrix pipe 20%
// idle). s_setprio(1) wraps the MFMA cluster (waves are barrier-free ->
// phase-diverse -> priority arbitration pays, per m191).
__global__ __launch_bounds__(256, 4) void attn_kernel(
    const short* __restrict__ q, const short* __restrict__ k,
    const short* __restrict__ v4, short* __restrict__ ctx,
    const int* __restrict__ pad_size_p, const int* __restrict__ single_pad_p) {
  __shared__ float comb[2][64][24];   // 12,288 B (16B-aligned per lane)
  int bid = blockIdx.x;
  int bh = bid & 63, slot2 = bid >> 6;   // bh fastest -> 8 heads/XCD (L2 fit)
  int wv = threadIdx.x >> 6, lane = threadIdx.x & 63;
  int rowhalf = wv & 1, keyhalf = wv >> 1;
  int l15 = lane & 15, quad = lane >> 4;

  int ps = pad_size_p[0];
  int sp2 = 2 * single_pad_p[0];
  int t0 = ps >> 6;                  // 15
  int kb0 = t0 * 64;                 // 960

  const short* Q = q + (size_t)bh * LPAD * DD;
  const short* K = k + (size_t)bh * LPAD * DD;
  const short* V4 = v4 + (size_t)bh * BHST;
  int lane4 = lane * 4;

  int row0 = slot2 * 64 + rowhalf * 32;   // 32 rows per wave-pair

  bf16x8 qf[2];
  qf[0] = *(const bf16x8*)(Q + (size_t)(row0 + l15) * DD + quad * 8);
  qf[1] = *(const bf16x8*)(Q + (size_t)(row0 + 16 + l15) * DD + quad * 8);

  // per-lane group window (for masking)
  int glo[2], ghi[2];
  // per-half uniform group span (for slice skipping)
  int fg_lo[2], fg_hi[2];
#pragma unroll
  for (int f = 0; f < 2; ++f) {
    int row = row0 + f * 16 + l15;
    int g = row / sp2;
    int lo = g * sp2, hi = lo + sp2;
    if (row >= ps) { lo = 0; hi = 0; }
    glo[f] = lo; ghi[f] = hi;
    int first = row0 + f * 16, last = first + 15;
    if (first >= ps) { fg_lo[f] = 0; fg_hi[f] = 0; }
    else { fg_lo[f] = (first / sp2) * sp2; fg_hi[f] = (last / sp2) * sp2 + sp2; }
  }

  const short one_bf = (short)0x3F80;              // bf16 1.0
  const bf16x4 onesf = {one_bf, one_bf, one_bf, one_bf};

  floatx4 lsum[2];
  lsum[0] = (floatx4){0.f, 0.f, 0.f, 0.f};
  lsum[1] = (floatx4){0.f, 0.f, 0.f, 0.f};
  floatx4 ot[2][2];
#pragma unroll
  for (int f = 0; f < 2; ++f)
#pragma unroll
    for (int db = 0; db < 2; ++db) ot[f][db] = (floatx4){0.f, 0.f, 0.f, 0.f};
  const floatx4 zf = (floatx4){0.f, 0.f, 0.f, 0.f};

  // one 64-key tile. mode: 0 = band-clean, 1 = band edge (ps/LL), 2 = group
  auto tile_work = [&](int kbase, int mode) {
    const short* vp = V4 + (size_t)(kbase >> 4) * 512;        // tile base
    const short* kp = K + (size_t)kbase * DD + l15 * DD + quad * 8;
    bf16x8 ka[4];
    bf16x4 va[2][4];
#pragma unroll
    for (int ns = 0; ns < 4; ++ns)
      ka[ns] = *(const bf16x8*)(kp + ns * 512);   // 16 keys * 32 shorts
#pragma unroll
    for (int db = 0; db < 2; ++db)
#pragma unroll
      for (int ns = 0; ns < 4; ++ns)
        va[db][ns] = *(const bf16x4*)(vp + (ns * 2 + db) * 256 + lane4);

    bool act[2][4];
    bf16x4 pt[2][4];
#pragma unroll
    for (int ns = 0; ns < 4; ++ns) {
      int ks0 = kbase + ns * 16;
#pragma unroll
      for (int f = 0; f < 2; ++f) {
        bool ov = (ks0 + 16 > fg_lo[f]) & (ks0 < fg_hi[f]);   // uniform
        bool a = true;
        if (mode == 2) a = ov;
        else if (mode == 1) a = (ks0 < LL) & ((ks0 + 16 > ps) | ov);
        act[f][ns] = a;
        if (a) {
          floatx4 st = __builtin_amdgcn_mfma_f32_16x16x32_bf16(ka[ns], qf[f], zf, 0, 0, 0);
          float e[4];
#pragma unroll
          for (int r = 0; r < 4; ++r) {
            float ev = __builtin_amdgcn_exp2f(st[r]);
            if (mode) {
              int key = ks0 + quad * 4 + r;
              int ing = (key >= glo[f]) & (key < ghi[f]);
              int vis = (mode == 2) ? ing : ((key < LL) & ((key >= ps) | ing));
              ev = vis ? ev : 0.f;
            }
            e[r] = ev;
          }
          pt[f][ns] = pack4(e[0], e[1], e[2], e[3]);
        }
      }
    }
    __builtin_amdgcn_s_setprio(1);
#pragma unroll
    for (int f = 0; f < 2; ++f)
#pragma unroll
      for (int ns = 0; ns < 4; ++ns)
        if (mode == 0 || act[f][ns]) {
          lsum[f] = __builtin_amdgcn_mfma_f32_16x16x16bf16_1k(onesf, pt[f][ns], lsum[f], 0, 0, 0);
#pragma unroll
          for (int db = 0; db < 2; ++db)
            ot[f][db] = __builtin_amdgcn_mfma_f32_16x16x16bf16_1k(va[db][ns], pt[f][ns], ot[f][db], 0, 0, 0);
        }
    __builtin_amdgcn_s_setprio(0);
  };

  // ---- group phase: keys < kb0 visible only inside own group ----
  // parity-split across keyhalf waves
  if (row0 < ps) {
    int rmaxd = row0 + 31;
    if (rmaxd >= ps) rmaxd = ps - 1;
    int c0 = (row0 / sp2) * sp2;
    int c1 = (rmaxd / sp2) * sp2 + sp2;
    if (c1 > ps) c1 = ps;
    int g_t0 = c0 >> 6;
    int g_end = (c1 + 63) >> 6;
    if (g_end > t0) g_end = t0;
    for (int jb = g_t0 + keyhalf; jb < g_end; jb += 2)
      tile_work(jb * 64, 2);
  }

  // ---- band phase: keys [kb0, LPAD), parity-split ----
  for (int kbase = kb0 + keyhalf * 64; kbase < LPAD; kbase += 128) {
    if ((kbase < ps) | (kbase + 64 > LL)) tile_work(kbase, 1);
    else tile_work(kbase, 0);
  }

  // ---- combine partials across keyhalf waves via LDS ----
  if (keyhalf == 1) {
    float* dst = &comb[rowhalf][lane][0];
    *(floatx4*)(dst + 0)  = ot[0][0];
    *(floatx4*)(dst + 4)  = ot[0][1];
    *(floatx4*)(dst + 8)  = ot[1][0];
    *(floatx4*)(dst + 12) = ot[1][1];
    *(floatx4*)(dst + 16) = lsum[0];
    *(floatx4*)(dst + 20) = lsum[1];
  }
  __syncthreads();
  if (keyhalf == 1) return;

  {
    const float* src = &comb[rowhalf][lane][0];
    ot[0][0] += *(const floatx4*)(src + 0);
    ot[0][1] += *(const floatx4*)(src + 4);
    ot[1][0] += *(const floatx4*)(src + 8);
    ot[1][1] += *(const floatx4*)(src + 12);
    lsum[0]  += *(const floatx4*)(src + 16);
    lsum[1]  += *(const floatx4*)(src + 20);
  }

  int b = bh >> 3, h = bh & 7;
#pragma unroll
  for (int f = 0; f < 2; ++f) {
    int row = row0 + f * 16 + l15;
    if (row >= LL) continue;
    float inv = 1.f / lsum[f][0];      // full 16-key x all-slice sum (MFMA)
    size_t base = ((size_t)b * LL + row) * EE + h * DD;
#pragma unroll
    for (int db = 0; db < 2; ++db) {
      short4 o;
      o.x = f2bf(ot[f][db][0] * inv);
      o.y = f2bf(ot[f][db][1] * inv);
      o.z = f2bf(ot[f][db][2] * inv);
      o.w = f2bf(ot[f][db][3] * inv);
      *(short4*)(ctx + base + db * 16 + quad * 4) = o;
    }
  }
}

// ---------------- Kernel C: out proj + residual + LayerNorm ---------------
#define OXS 260
__global__ __launch_bounds__(256) void outln_kernel(
    const short* __restrict__ ctx, const short* __restrict__ ow,
    const float* __restrict__ ob, const float* __restrict__ x,
    const float* __restrict__ lg, const float* __restrict__ lb,
    float* __restrict__ out) {
  __shared__ float xs[16 * OXS];        // residual x tile (coalesced staging)
  __shared__ float red[4][16][2];
  int mtile = blockIdx.x;               // 0..949, 16 rows each (exact)
  int wv = threadIdx.x >> 6, lane = threadIdx.x & 63;
  int l15 = lane & 15, quad = lane >> 4;
  int rowbase = mtile * 16;

  float4 xv[4];
#pragma unroll
  for (int i = 0; i < 4; ++i) {
    int row = (threadIdx.x >> 6) + i * 4;
    int col = (threadIdx.x & 63) * 4;
    xv[i] = *(const float4*)(x + (size_t)(rowbase + row) * EE + col);
  }
  const short* crow = ctx + (size_t)(rowbase + l15) * EE;
  bf16x8 ca[8];
#pragma unroll
  for (int ks = 0; ks < 8; ++ks)
    ca[ks] = *(const bf16x8*)(crow + ks * 32 + quad * 8);
  bf16x8 wr[8][4];
#pragma unroll
  for (int ks = 0; ks < 8; ++ks)
#pragma unroll
    for (int ns = 0; ns < 4; ++ns) {
      int frow = wv * 64 + ns * 16 + l15;
      wr[ks][ns] = *(const bf16x8*)(ow + (size_t)frow * EE + ks * 32 + quad * 8);
    }
  asm volatile("" ::: "memory");

#pragma unroll
  for (int i = 0; i < 4; ++i) {
    int row = (threadIdx.x >> 6) + i * 4;
    int col = (threadIdx.x & 63) * 4;
    *(float4*)&xs[row * OXS + col] = xv[i];
  }
  __syncthreads();

  floatx4 acc[4];
#pragma unroll
  for (int i = 0; i < 4; ++i) acc[i] = (floatx4){0.f, 0.f, 0.f, 0.f};
#pragma unroll
  for (int ks = 0; ks < 8; ++ks)
#pragma unroll
    for (int ns = 0; ns < 4; ++ns)
      acc[ns] = __builtin_amdgcn_mfma_f32_16x16x32_bf16(ca[ks], wr[ks][ns], acc[ns], 0, 0, 0);

  float obv[4], lgv[4], lbv[4];
#pragma unroll
  for (int ns = 0; ns < 4; ++ns) {
    int c = wv * 64 + ns * 16 + l15;
    obv[ns] = ob[c]; lgv[ns] = lg[c]; lbv[ns] = lb[c];
  }

  float y[4][4];                         // [ns][r]
  float s1[4] = {0.f, 0.f, 0.f, 0.f}, s2[4] = {0.f, 0.f, 0.f, 0.f};
#pragma unroll
  for (int r = 0; r < 4; ++r) {
    int rr = quad * 4 + r;
#pragma unroll
    for (int ns = 0; ns < 4; ++ns) {
      int c = wv * 64 + ns * 16 + l15;
      float yy = acc[ns][r] + obv[ns] + xs[rr * OXS + c];
      y[ns][r] = yy;
      s1[r] += yy;
      s2[r] += yy * yy;
    }
  }
#pragma unroll
  for (int r = 0; r < 4; ++r) {
#pragma unroll
    for (int off = 1; off < 16; off <<= 1) {
      s1[r] += __shfl_xor(s1[r], off, 16);
      s2[r] += __shfl_xor(s2[r], off, 16);
    }
  }
  if (l15 == 0) {
#pragma unroll
    for (int r = 0; r < 4; ++r) {
      red[wv][quad * 4 + r][0] = s1[r];
      red[wv][quad * 4 + r][1] = s2[r];
    }
  }
  __syncthreads();
#pragma unroll
  for (int r = 0; r < 4; ++r) {
    int rr = quad * 4 + r;
    float t1 = 0.f, t2 = 0.f;
#pragma unroll
    for (int w2 = 0; w2 < 4; ++w2) { t1 += red[w2][rr][0]; t2 += red[w2][rr][1]; }
    float mu = t1 * (1.f / 256.f);
    float var = t2 * (1.f / 256.f) - mu * mu;
    float rs = rsqrtf(var + 1e-5f);
    int tok = rowbase + rr;
#pragma unroll
    for (int ns = 0; ns < 4; ++ns) {
      int c = wv * 64 + ns * 16 + l15;
      out[(size_t)tok * EE + c] = (y[ns][r] - mu) * rs * lgv[ns] + lbv[ns];
    }
  }
}

extern "C" void kernel_launch(void* const* d_in, const int* in_sizes, int n_in,
                              void* d_out, int out_size, void* d_ws, size_t ws_size,
                              hipStream_t stream) {
  const float* x  = (const float*)d_in[0];
  const float* w  = (const float*)d_in[1];
  const float* wb = (const float*)d_in[2];
  const float* ow = (const float*)d_in[3];
  const float* ob = (const float*)d_in[4];
  const float* lg = (const float*)d_in[5];
  const float* lb = (const float*)d_in[6];
  const int* ps = (const int*)d_in[8];   // pad_size
  const int* sp = (const int*)d_in[9];   // single_pad

  short* wbb = (short*)d_ws;                       // 768*256 bf16
  short* owb = wbb + (size_t)768 * EE;             // 256*256 bf16
  short* qw  = owb + (size_t)256 * EE;             // 64*1920*32 bf16 (pre-scaled)
  short* kw  = qw + (size_t)64 * LPAD * DD;
  short* v4w = kw + (size_t)64 * LPAD * DD;        // fragment-layout V
  // xbf (15264*264 shorts, 8.06 MB) and ctx (15200*256 shorts, 7.78 MB)
  // have disjoint lifetimes -> alias them in the same workspace region.
  short* xbf = v4w + (size_t)64 * BHST;
  short* ctx = xbf;

  cvt_kernel<<<CVT_TOT / 256, 256, 0, stream>>>(w, ow, x, wbb, owb, xbf);
  qkv_kernel<<<240 * 6, 256, 0, stream>>>(xbf, wbb, wb, qw, kw, v4w);
  attn_kernel<<<30 * 64, 256, 0, stream>>>(qw, kw, v4w, ctx, ps, sp);
  outln_kernel<<<950, 256, 0, stream>>>(ctx, owb, ob, x, lg, lb, (float*)d_out);
}

// Round 13
// 163.547 us; speedup vs baseline: 1.8648x; 1.0104x over previous
//
#include <hip/hip_runtime.h>
#include <math.h>

#define BB 8
#define LL 1900
#define LPAD 1920
#define EE 256
#define HH 8
#define DD 32
#define MTOK (BB*LL)              // 15200
#define SCALE 0.17677669529663687f
#define LOG2E 1.4426950408889634f
#define NKB 120                   // keyblocks of 16 per (b,h)
#define BHST (NKB*2*256)          // 61440 shorts per (b,h) in v4

typedef __attribute__((ext_vector_type(8))) short bf16x8;
typedef __attribute__((ext_vector_type(4))) short bf16x4;
typedef __attribute__((ext_vector_type(4))) float floatx4;
typedef __attribute__((ext_vector_type(2))) unsigned uintx2;

__device__ inline short f2bf(float f) {
  unsigned u = __builtin_bit_cast(unsigned, f);
  u += 0x7FFF + ((u >> 16) & 1);
  return (short)(u >> 16);
}

// pack 4 fp32 -> 4 bf16 (truncate) via v_perm_b32
__device__ inline bf16x4 pack4(float s0, float s1, float s2, float s3) {
  uintx2 u;
  u.x = __builtin_amdgcn_perm(__builtin_bit_cast(unsigned, s1),
                              __builtin_bit_cast(unsigned, s0), 0x07060302u);
  u.y = __builtin_amdgcn_perm(__builtin_bit_cast(unsigned, s3),
                              __builtin_bit_cast(unsigned, s2), 0x07060302u);
  return __builtin_bit_cast(bf16x4, u);
}

// async global->LDS DMA, 16 B per lane; lds base must be wave-uniform
__device__ inline void load_lds16(const void* g, void* l) {
  __builtin_amdgcn_global_load_lds(
      (const __attribute__((address_space(1))) unsigned*)g,
      (__attribute__((address_space(3))) unsigned*)l, 16, 0, 0);
}

// ---------------- Kernel 0: fp32 -> bf16 for in_proj_w, out_w, AND x ------
// x lands padded: [XROWS][XSTR] bf16, XSTR=264 shorts (528 B = 33*16 B:
// 16B-multiple for linear DMA; 132 dw == 4 (mod 32) -> 2-way-free banks
// for the stride-XSTR A-fragment reads). Rows >= MTOK zero-filled.
#define CVT_W4  49152             // 196608/4
#define CVT_OW4 16384             // 65536/4
#define XROWS 15264
#define XSTR  264
#define CVT_X4 (XROWS*64)         // 976896
#define CVT_TOT (CVT_W4 + CVT_OW4 + CVT_X4)   // 1042432 = 4072*256
__global__ __launch_bounds__(256) void cvt_kernel(
    const float* __restrict__ w, const float* __restrict__ ow,
    const float* __restrict__ x,
    short* __restrict__ wb, short* __restrict__ owb, short* __restrict__ xb) {
  int i = blockIdx.x * 256 + threadIdx.x;
  if (i < CVT_W4 + CVT_OW4) {
    const float* src; short* dst; int off;
    if (i < CVT_W4) { src = w; dst = wb; off = i; }
    else { src = ow; dst = owb; off = i - CVT_W4; }
    float4 v = *(const float4*)(src + (size_t)off * 4);
    short4 o;
    o.x = f2bf(v.x); o.y = f2bf(v.y); o.z = f2bf(v.z); o.w = f2bf(v.w);
    *(short4*)(dst + (size_t)off * 4) = o;
  } else {
    int j = i - (CVT_W4 + CVT_OW4);
    int row = j >> 6, seg = j & 63;
    short4 o; o.x = 0; o.y = 0; o.z = 0; o.w = 0;
    if (row < MTOK) {
      float4 v = *(const float4*)(x + (size_t)row * EE + seg * 4);
      o.x = f2bf(v.x); o.y = f2bf(v.y); o.z = f2bf(v.z); o.w = f2bf(v.w);
    }
    *(short4*)(xb + (size_t)row * XSTR + seg * 4) = o;
  }
}

// ---------------- Kernel A: QKV projection, LDS-shared w, A-in-regs -------
// 3 ntiles per block (grid 240x4): x-DMA redundancy 6x -> 4x, 1.5x MFMA
// per block. accs[3][4]=48 VGPR + af 32 ~ 100, under the (256,4) cap.
#define XWSH (16*XSTR)            // 4224 shorts per wave x-slice
#define LDS_SH 17280              // 34,560 B: fits x-slices / w-tile / cbuf
__global__ __launch_bounds__(256, 4) void qkv_kernel(
    const short* __restrict__ xbf, const short* __restrict__ w,
    const float* __restrict__ bias, short* __restrict__ q,
    short* __restrict__ k, short* __restrict__ v4) {
  __shared__ short lds[LDS_SH];
  int bid = blockIdx.x;
  int mtile = bid % 240, ngrp = bid / 240;   // ngrp 0..3 -> ntiles 3g..3g+2
  if (mtile >= 238) return;
  int wv = threadIdx.x >> 6, lane = threadIdx.x & 63;
  int l15 = lane & 15, quad = lane >> 4;

  // ---- DMA phase: 16 bf16 rows = 8448 B/wave, 9 x 1 KB linear chunks ----
  const short* gsrc = xbf + (size_t)(mtile * 64 + wv * 16) * XSTR;
  char* xw = (char*)&lds[wv * XWSH];
#pragma unroll
  for (int i = 0; i < 9; ++i)
    load_lds16((const char*)gsrc + i * 1024 + lane * 16, xw + i * 1024);
  asm volatile("s_waitcnt vmcnt(0)" ::: "memory");

  // ---- A-fragments to registers (wave-private slice; no barrier needed) --
  bf16x8 af[8];
#pragma unroll
  for (int ks = 0; ks < 8; ++ks)
    af[ks] = *(const bf16x8*)&lds[wv * XWSH + l15 * XSTR + ks * 32 + quad * 8];
  __syncthreads();   // all A-reads done before w-tile overwrites lds

  floatx4 accs[3][4];
#pragma unroll
  for (int s = 0; s < 3; ++s)
#pragma unroll
    for (int i = 0; i < 4; ++i) accs[s][i] = (floatx4){0.f, 0.f, 0.f, 0.f};

#pragma unroll
  for (int s = 0; s < 3; ++s) {
    int ntile = ngrp * 3 + s;
    // stage 64x256 w-tile -> padded [64][XSTR] (coalesced global reads)
    const short* wsub = w + (size_t)ntile * 64 * EE;
#pragma unroll
    for (int i = 0; i < 8; ++i) {
      int c = threadIdx.x + i * 256;      // 0..2047 16B-chunks
      int row = c >> 5, col = (c & 31) * 8;
      *(bf16x8*)&lds[row * XSTR + col] = *(const bf16x8*)(wsub + row * EE + col);
    }
    __syncthreads();
#pragma unroll
    for (int ks = 0; ks < 8; ++ks)
#pragma unroll
      for (int ns = 0; ns < 4; ++ns) {
        bf16x8 bfr = *(const bf16x8*)&lds[(ns * 16 + l15) * XSTR + ks * 32 + quad * 8];
        accs[s][ns] = __builtin_amdgcn_mfma_f32_16x16x32_bf16(af[ks], bfr, accs[s][ns], 0, 0, 0);
      }
    __syncthreads();   // done reading w-tile before restage / cbuf reuse
  }

  // ---- epilogue per sub-ntile: bias(+scale), LDS transpose, stores ----
  short* cbuf = (short*)lds;               // 64*72 shorts, aliases lds
  int t0tok = mtile * 64;
  int b0 = t0tok / LL;
  bool uni = (b0 == (t0tok + 63) / LL) && (t0tok + 63 < MTOK);

#pragma unroll
  for (int s = 0; s < 3; ++s) {
    int ntile = ngrp * 3 + s;
    float qs = (ntile < 4) ? (SCALE * LOG2E) : 1.0f;
#pragma unroll
    for (int ns = 0; ns < 4; ++ns) {
      float bv = bias[ntile * 64 + ns * 16 + l15];
#pragma unroll
      for (int r = 0; r < 4; ++r)
        cbuf[(wv * 16 + quad * 4 + r) * 72 + ns * 16 + l15] =
            f2bf((accs[s][ns][r] + bv) * qs);
    }
    __syncthreads();

    int which = ntile >> 2;          // 0=q 1=k 2=v
    int fbase = (ntile & 3) * 64;

    if (which < 2) {
      short* dst0 = which ? k : q;
      int tl = threadIdx.x >> 2, seg = threadIdx.x & 3;
      int tok = t0tok + tl;
      if (tok < MTOK) {
        int b = uni ? b0 : tok / LL;
        int l = tok - b * LL;
        int fl = seg * 16;
        int h = (fbase + fl) >> 5;
        int d = (fbase + fl) & 31;
        size_t base = ((size_t)(b * HH + h) * LPAD + l) * DD + d;
        bf16x8 v0 = *(bf16x8*)(&cbuf[tl * 72 + fl]);
        bf16x8 v1 = *(bf16x8*)(&cbuf[tl * 72 + fl + 8]);
        *(bf16x8*)(dst0 + base) = v0;
        *(bf16x8*)(dst0 + base + 8) = v1;
      }
    } else {
      // V -> fragment layout v4
      int fl = threadIdx.x >> 2, ls = threadIdx.x & 3;
      int h = (fbase + fl) >> 5;
      int d = (fbase + fl) & 31;
      int db = d >> 4, dl = d & 15;
      if (uni) {
        int l0 = t0tok - b0 * LL + ls * 16;   // 4-aligned (1900 % 4 == 0)
        short* Vb = v4 + (size_t)(b0 * HH + h) * BHST;
#pragma unroll
        for (int g4 = 0; g4 < 4; ++g4) {
          int l = l0 + g4 * 4;
          int kb = l >> 4, qd = (l >> 2) & 3; // l&3 == 0
          int tb = ls * 16 + g4 * 4;
          short4 vv;
          vv.x = cbuf[(tb + 0) * 72 + fl];
          vv.y = cbuf[(tb + 1) * 72 + fl];
          vv.z = cbuf[(tb + 2) * 72 + fl];
          vv.w = cbuf[(tb + 3) * 72 + fl];
          *(short4*)(Vb + (size_t)(kb * 2 + db) * 256 + (dl + 16 * qd) * 4) = vv;
        }
      } else {
#pragma unroll
        for (int i = 0; i < 16; ++i) {
          int tl = ls * 16 + i;
          int tok = t0tok + tl;
          if (tok < MTOK) {
            int b = tok / LL;
            int l = tok - b * LL;
            int kb = l >> 4, qd = (l >> 2) & 3, j = l & 3;
            v4[(size_t)(b * HH + h) * BHST + (size_t)(kb * 2 + db) * 256 +
               (dl + 16 * qd) * 4 + j] = cbuf[tl * 72 + fl];
          }
        }
      }
    }
    __syncthreads();   // cbuf free before next sub-ntile overwrites it
  }
}

// ---------------- Kernel B: flash attention, f=4 key-split ----------------
// NEW: 64 rows per wave (qf[4]) -- each K/V tile load now feeds 4 q-
// fragments instead of 2: total waves halve (3840) and K/V L2 traffic
// halves. This tests the one mechanism untouched by R7/R11/R12 (all
// flat): per-wave arithmetic intensity. Live state ~150 VGPR ->
// __launch_bounds__(256,2) (cap 256, NO spill possible -- R10 lesson).
// 4-wave blocks = (rowhalf, keyhalf); partials combine linearly via LDS.
__global__ __launch_bounds__(256, 2) void attn_kernel(
    const short* __restrict__ q, const short* __restrict__ k,
    const short* __restrict__ v4, short* __restrict__ ctx,
    const int* __restrict__ pad_size_p, const int* __restrict__ single_pad_p) {
  __shared__ float comb[2][64][44];   // 22,528 B; stride 44 spreads banks
  int bid = blockIdx.x;
  int bh = bid & 63, slot2 = bid >> 6;   // bh fastest -> 8 heads/XCD (L2 fit)
  int wv = threadIdx.x >> 6, lane = threadIdx.x & 63;
  int rowhalf = wv & 1, keyhalf = wv >> 1;
  int l15 = lane & 15, quad = lane >> 4;

  int ps = pad_size_p[0];
  int sp2 = 2 * single_pad_p[0];
  int t0 = ps >> 6;                  // 15
  int kb0 = t0 * 64;                 // 960

  const short* Q = q + (size_t)bh * LPAD * DD;
  const short* K = k + (size_t)bh * LPAD * DD;
  const short* V4 = v4 + (size_t)bh * BHST;
  int lane4 = lane * 4;

  int row0 = slot2 * 128 + rowhalf * 64;   // 64 rows per wave

  bf16x8 qf[4];
#pragma unroll
  for (int f = 0; f < 4; ++f)
    qf[f] = *(const bf16x8*)(Q + (size_t)(row0 + f * 16 + l15) * DD + quad * 8);

  // per-lane group window (for masking)
  int glo[4], ghi[4];
  // per-16-row-half uniform group span (for slice skipping)
  int fg_lo[4], fg_hi[4];
#pragma unroll
  for (int f = 0; f < 4; ++f) {
    int row = row0 + f * 16 + l15;
    int g = row / sp2;
    int lo = g * sp2, hi = lo + sp2;
    if (row >= ps) { lo = 0; hi = 0; }
    glo[f] = lo; ghi[f] = hi;
    int first = row0 + f * 16, last = first + 15;
    if (first >= ps) { fg_lo[f] = 0; fg_hi[f] = 0; }
    else { fg_lo[f] = (first / sp2) * sp2; fg_hi[f] = (last / sp2) * sp2 + sp2; }
  }

  const short one_bf = (short)0x3F80;              // bf16 1.0
  const bf16x4 onesf = {one_bf, one_bf, one_bf, one_bf};

  floatx4 lsum[4];
  floatx4 ot[4][2];
#pragma unroll
  for (int f = 0; f < 4; ++f) {
    lsum[f] = (floatx4){0.f, 0.f, 0.f, 0.f};
#pragma unroll
    for (int db = 0; db < 2; ++db) ot[f][db] = (floatx4){0.f, 0.f, 0.f, 0.f};
  }
  const floatx4 zf = (floatx4){0.f, 0.f, 0.f, 0.f};

  // one 64-key tile. mode: 0 = band-clean, 1 = band edge (ps/LL), 2 = group
  auto tile_work = [&](int kbase, int mode) {
    const short* vp = V4 + (size_t)(kbase >> 4) * 512;        // tile base
    const short* kp = K + (size_t)kbase * DD + l15 * DD + quad * 8;
    bf16x8 ka[4];
    bf16x4 va[2][4];
#pragma unroll
    for (int ns = 0; ns < 4; ++ns)
      ka[ns] = *(const bf16x8*)(kp + ns * 512);   // 16 keys * 32 shorts
#pragma unroll
    for (int db = 0; db < 2; ++db)
#pragma unroll
      for (int ns = 0; ns < 4; ++ns)
        va[db][ns] = *(const bf16x4*)(vp + (ns * 2 + db) * 256 + lane4);

    bool act[4][4];
    bf16x4 pt[4][4];
#pragma unroll
    for (int ns = 0; ns < 4; ++ns) {
      int ks0 = kbase + ns * 16;
#pragma unroll
      for (int f = 0; f < 4; ++f) {
        bool ov = (ks0 + 16 > fg_lo[f]) & (ks0 < fg_hi[f]);   // uniform
        bool a = true;
        if (mode == 2) a = ov;
        else if (mode == 1) a = (ks0 < LL) & ((ks0 + 16 > ps) | ov);
        act[f][ns] = a;
        if (a) {
          floatx4 st = __builtin_amdgcn_mfma_f32_16x16x32_bf16(ka[ns], qf[f], zf, 0, 0, 0);
          float e[4];
#pragma unroll
          for (int r = 0; r < 4; ++r) {
            float ev = __builtin_amdgcn_exp2f(st[r]);
            if (mode) {
              int key = ks0 + quad * 4 + r;
              int ing = (key >= glo[f]) & (key < ghi[f]);
              int vis = (mode == 2) ? ing : ((key < LL) & ((key >= ps) | ing));
              ev = vis ? ev : 0.f;
            }
            e[r] = ev;
          }
          pt[f][ns] = pack4(e[0], e[1], e[2], e[3]);
        }
      }
    }
    __builtin_amdgcn_s_setprio(1);
#pragma unroll
    for (int f = 0; f < 4; ++f)
#pragma unroll
      for (int ns = 0; ns < 4; ++ns)
        if (mode == 0 || act[f][ns]) {
          lsum[f] = __builtin_amdgcn_mfma_f32_16x16x16bf16_1k(onesf, pt[f][ns], lsum[f], 0, 0, 0);
#pragma unroll
          for (int db = 0; db < 2; ++db)
            ot[f][db] = __builtin_amdgcn_mfma_f32_16x16x16bf16_1k(va[db][ns], pt[f][ns], ot[f][db], 0, 0, 0);
        }
    __builtin_amdgcn_s_setprio(0);
  };

  // ---- group phase: keys < kb0 visible only inside own group ----
  // parity-split across keyhalf waves
  if (row0 < ps) {
    int rmaxd = row0 + 63;
    if (rmaxd >= ps) rmaxd = ps - 1;
    int c0 = (row0 / sp2) * sp2;
    int c1 = (rmaxd / sp2) * sp2 + sp2;
    if (c1 > ps) c1 = ps;
    int g_t0 = c0 >> 6;
    int g_end = (c1 + 63) >> 6;
    if (g_end > t0) g_end = t0;
    for (int jb = g_t0 + keyhalf; jb < g_end; jb += 2)
      tile_work(jb * 64, 2);
  }

  // ---- band phase: keys [kb0, LPAD), parity-split ----
  for (int kbase = kb0 + keyhalf * 64; kbase < LPAD; kbase += 128) {
    if ((kbase < ps) | (kbase + 64 > LL)) tile_work(kbase, 1);
    else tile_work(kbase, 0);
  }

  // ---- combine partials across keyhalf waves via LDS ----
  if (keyhalf == 1) {
    float* dst = &comb[rowhalf][lane][0];
#pragma unroll
    for (int f = 0; f < 4; ++f) {
      *(floatx4*)(dst + f * 8)     = ot[f][0];
      *(floatx4*)(dst + f * 8 + 4) = ot[f][1];
      dst[32 + f] = lsum[f][0];
    }
  }
  __syncthreads();
  if (keyhalf == 1) return;

  {
    const float* src = &comb[rowhalf][lane][0];
#pragma unroll
    for (int f = 0; f < 4; ++f) {
      ot[f][0] += *(const floatx4*)(src + f * 8);
      ot[f][1] += *(const floatx4*)(src + f * 8 + 4);
      lsum[f][0] += src[32 + f];
    }
  }

  int b = bh >> 3, h = bh & 7;
#pragma unroll
  for (int f = 0; f < 4; ++f) {
    int row = row0 + f * 16 + l15;
    if (row >= LL) continue;
    float inv = 1.f / lsum[f][0];      // full denominator (MFMA-summed)
    size_t base = ((size_t)b * LL + row) * EE + h * DD;
#pragma unroll
    for (int db = 0; db < 2; ++db) {
      short4 o;
      o.x = f2bf(ot[f][db][0] * inv);
      o.y = f2bf(ot[f][db][1] * inv);
      o.z = f2bf(ot[f][db][2] * inv);
      o.w = f2bf(ot[f][db][3] * inv);
      *(short4*)(ctx + base + db * 16 + quad * 4) = o;
    }
  }
}

// ---------------- Kernel C: out proj + residual + LayerNorm ---------------
#define OXS 260
__global__ __launch_bounds__(256) void outln_kernel(
    const short* __restrict__ ctx, const short* __restrict__ ow,
    const float* __restrict__ ob, const float* __restrict__ x,
    const float* __restrict__ lg, const float* __restrict__ lb,
    float* __restrict__ out) {
  __shared__ float xs[16 * OXS];        // residual x tile (coalesced staging)
  __shared__ float red[4][16][2];
  int mtile = blockIdx.x;               // 0..949, 16 rows each (exact)
  int wv = threadIdx.x >> 6, lane = threadIdx.x & 63;
  int l15 = lane & 15, quad = lane >> 4;
  int rowbase = mtile * 16;

  float4 xv[4];
#pragma unroll
  for (int i = 0; i < 4; ++i) {
    int row = (threadIdx.x >> 6) + i * 4;
    int col = (threadIdx.x & 63) * 4;
    xv[i] = *(const float4*)(x + (size_t)(rowbase + row) * EE + col);
  }
  const short* crow = ctx + (size_t)(rowbase + l15) * EE;
  bf16x8 ca[8];
#pragma unroll
  for (int ks = 0; ks < 8; ++ks)
    ca[ks] = *(const bf16x8*)(crow + ks * 32 + quad * 8);
  bf16x8 wr[8][4];
#pragma unroll
  for (int ks = 0; ks < 8; ++ks)
#pragma unroll
    for (int ns = 0; ns < 4; ++ns) {
      int frow = wv * 64 + ns * 16 + l15;
      wr[ks][ns] = *(const bf16x8*)(ow + (size_t)frow * EE + ks * 32 + quad * 8);
    }
  asm volatile("" ::: "memory");

#pragma unroll
  for (int i = 0; i < 4; ++i) {
    int row = (threadIdx.x >> 6) + i * 4;
    int col = (threadIdx.x & 63) * 4;
    *(float4*)&xs[row * OXS + col] = xv[i];
  }
  __syncthreads();

  floatx4 acc[4];
#pragma unroll
  for (int i = 0; i < 4; ++i) acc[i] = (floatx4){0.f, 0.f, 0.f, 0.f};
#pragma unroll
  for (int ks = 0; ks < 8; ++ks)
#pragma unroll
    for (int ns = 0; ns < 4; ++ns)
      acc[ns] = __builtin_amdgcn_mfma_f32_16x16x32_bf16(ca[ks], wr[ks][ns], acc[ns], 0, 0, 0);

  float obv[4], lgv[4], lbv[4];
#pragma unroll
  for (int ns = 0; ns < 4; ++ns) {
    int c = wv * 64 + ns * 16 + l15;
    obv[ns] = ob[c]; lgv[ns] = lg[c]; lbv[ns] = lb[c];
  }

  float y[4][4];                         // [ns][r]
  float s1[4] = {0.f, 0.f, 0.f, 0.f}, s2[4] = {0.f, 0.f, 0.f, 0.f};
#pragma unroll
  for (int r = 0; r < 4; ++r) {
    int rr = quad * 4 + r;
#pragma unroll
    for (int ns = 0; ns < 4; ++ns) {
      int c = wv * 64 + ns * 16 + l15;
      float yy = acc[ns][r] + obv[ns] + xs[rr * OXS + c];
      y[ns][r] = yy;
      s1[r] += yy;
      s2[r] += yy * yy;
    }
  }
#pragma unroll
  for (int r = 0; r < 4; ++r) {
#pragma unroll
    for (int off = 1; off < 16; off <<= 1) {
      s1[r] += __shfl_xor(s1[r], off, 16);
      s2[r] += __shfl_xor(s2[r], off, 16);
    }
  }
  if (l15 == 0) {
#pragma unroll
    for (int r = 0; r < 4; ++r) {
      red[wv][quad * 4 + r][0] = s1[r];
      red[wv][quad * 4 + r][1] = s2[r];
    }
  }
  __syncthreads();
#pragma unroll
  for (int r = 0; r < 4; ++r) {
    int rr = quad * 4 + r;
    float t1 = 0.f, t2 = 0.f;
#pragma unroll
    for (int w2 = 0; w2 < 4; ++w2) { t1 += red[w2][rr][0]; t2 += red[w2][rr][1]; }
    float mu = t1 * (1.f / 256.f);
    float var = t2 * (1.f / 256.f) - mu * mu;
    float rs = rsqrtf(var + 1e-5f);
    int tok = rowbase + rr;
#pragma unroll
    for (int ns = 0; ns < 4; ++ns) {
      int c = wv * 64 + ns * 16 + l15;
      out[(size_t)tok * EE + c] = (y[ns][r] - mu) * rs * lgv[ns] + lbv[ns];
    }
  }
}

extern "C" void kernel_launch(void* const* d_in, const int* in_sizes, int n_in,
                              void* d_out, int out_size, void* d_ws, size_t ws_size,
                              hipStream_t stream) {
  const float* x  = (const float*)d_in[0];
  const float* w  = (const float*)d_in[1];
  const float* wb = (const float*)d_in[2];
  const float* ow = (const float*)d_in[3];
  const float* ob = (const float*)d_in[4];
  const float* lg = (const float*)d_in[5];
  const float* lb = (const float*)d_in[6];
  const int* ps = (const int*)d_in[8];   // pad_size
  const int* sp = (const int*)d_in[9];   // single_pad

  short* wbb = (short*)d_ws;                       // 768*256 bf16
  short* owb = wbb + (size_t)768 * EE;             // 256*256 bf16
  short* qw  = owb + (size_t)256 * EE;             // 64*1920*32 bf16 (pre-scaled)
  short* kw  = qw + (size_t)64 * LPAD * DD;
  short* v4w = kw + (size_t)64 * LPAD * DD;        // fragment-layout V
  // xbf (15264*264 shorts, 8.06 MB) and ctx (15200*256 shorts, 7.78 MB)
  // have disjoint lifetimes -> alias them in the same workspace region.
  short* xbf = v4w + (size_t)64 * BHST;
  short* ctx = xbf;

  cvt_kernel<<<CVT_TOT / 256, 256, 0, stream>>>(w, ow, x, wbb, owb, xbf);
  qkv_kernel<<<240 * 4, 256, 0, stream>>>(xbf, wbb, wb, qw, kw, v4w);
  attn_kernel<<<15 * 64, 256, 0, stream>>>(qw, kw, v4w, ctx, ps, sp);
  outln_kernel<<<950, 256, 0, stream>>>(ctx, owb, ob, x, lg, lb, (float*)d_out);
}

// Round 14
// 158.562 us; speedup vs baseline: 1.9234x; 1.0314x over previous
//
#include <hip/hip_runtime.h>
#include <math.h>

#define BB 8
#define LL 1900
#define LPAD 1920
#define EE 256
#define HH 8
#define DD 32
#define MTOK (BB*LL)              // 15200
#define SCALE 0.17677669529663687f
#define LOG2E 1.4426950408889634f
#define NKB 120                   // keyblocks of 16 per (b,h)
#define BHST (NKB*2*256)          // 61440 shorts per (b,h) in v4

typedef __attribute__((ext_vector_type(8))) short bf16x8;
typedef __attribute__((ext_vector_type(4))) short bf16x4;
typedef __attribute__((ext_vector_type(4))) float floatx4;
typedef __attribute__((ext_vector_type(2))) unsigned uintx2;

__device__ inline short f2bf(float f) {
  unsigned u = __builtin_bit_cast(unsigned, f);
  u += 0x7FFF + ((u >> 16) & 1);
  return (short)(u >> 16);
}

// pack 4 fp32 -> 4 bf16 (truncate) via v_perm_b32
__device__ inline bf16x4 pack4(float s0, float s1, float s2, float s3) {
  uintx2 u;
  u.x = __builtin_amdgcn_perm(__builtin_bit_cast(unsigned, s1),
                              __builtin_bit_cast(unsigned, s0), 0x07060302u);
  u.y = __builtin_amdgcn_perm(__builtin_bit_cast(unsigned, s3),
                              __builtin_bit_cast(unsigned, s2), 0x07060302u);
  return __builtin_bit_cast(bf16x4, u);
}

// async global->LDS DMA, 16 B per lane; lds base must be wave-uniform
__device__ inline void load_lds16(const void* g, void* l) {
  __builtin_amdgcn_global_load_lds(
      (const __attribute__((address_space(1))) unsigned*)g,
      (__attribute__((address_space(3))) unsigned*)l, 16, 0, 0);
}

// ---------------- Kernel 0: fp32 -> bf16 for in_proj_w, out_w, AND x ------
#define CVT_W4  49152             // 196608/4
#define CVT_OW4 16384             // 65536/4
#define XROWS 15264
#define XSTR  264
#define CVT_X4 (XROWS*64)         // 976896
#define CVT_TOT (CVT_W4 + CVT_OW4 + CVT_X4)   // 1042432 = 4072*256
__global__ __launch_bounds__(256) void cvt_kernel(
    const float* __restrict__ w, const float* __restrict__ ow,
    const float* __restrict__ x,
    short* __restrict__ wb, short* __restrict__ owb, short* __restrict__ xb) {
  int i = blockIdx.x * 256 + threadIdx.x;
  if (i < CVT_W4 + CVT_OW4) {
    const float* src; short* dst; int off;
    if (i < CVT_W4) { src = w; dst = wb; off = i; }
    else { src = ow; dst = owb; off = i - CVT_W4; }
    float4 v = *(const float4*)(src + (size_t)off * 4);
    short4 o;
    o.x = f2bf(v.x); o.y = f2bf(v.y); o.z = f2bf(v.z); o.w = f2bf(v.w);
    *(short4*)(dst + (size_t)off * 4) = o;
  } else {
    int j = i - (CVT_W4 + CVT_OW4);
    int row = j >> 6, seg = j & 63;
    short4 o; o.x = 0; o.y = 0; o.z = 0; o.w = 0;
    if (row < MTOK) {
      float4 v = *(const float4*)(x + (size_t)row * EE + seg * 4);
      o.x = f2bf(v.x); o.y = f2bf(v.y); o.z = f2bf(v.z); o.w = f2bf(v.w);
    }
    *(short4*)(xb + (size_t)row * XSTR + seg * 4) = o;
  }
}

// ---------------- Kernel A: QKV projection, LDS-shared w, A-in-regs -------
// V fragment layout (PAIR-INTERLEAVED, R14): per 32-key pair-block kbp,
//   v4[bh][kbp (60)][db (2)][lane (64)][8] with
//   short[lane*8 + half*4 + j] = V[d = db*16+(lane&15)]
//                                 [key = kbp*32 + half*16 + (lane>>4)*4 + j]
// so ONE bf16x8 load per lane serves TWO PV slices (halves = register
// aliases). Halves attention's va load count.
#define XWSH (16*XSTR)            // 4224 shorts per wave x-slice
#define LDS_SH 17280              // 34,560 B: fits x-slices / w-tile / cbuf
__global__ __launch_bounds__(256, 4) void qkv_kernel(
    const short* __restrict__ xbf, const short* __restrict__ w,
    const float* __restrict__ bias, short* __restrict__ q,
    short* __restrict__ k, short* __restrict__ v4) {
  __shared__ short lds[LDS_SH];
  int bid = blockIdx.x;
  int mtile = bid % 240, ngrp = bid / 240;   // ngrp 0..3 -> ntiles 3g..3g+2
  if (mtile >= 238) return;
  int wv = threadIdx.x >> 6, lane = threadIdx.x & 63;
  int l15 = lane & 15, quad = lane >> 4;

  // ---- DMA phase: 16 bf16 rows = 8448 B/wave, 9 x 1 KB linear chunks ----
  const short* gsrc = xbf + (size_t)(mtile * 64 + wv * 16) * XSTR;
  char* xw = (char*)&lds[wv * XWSH];
#pragma unroll
  for (int i = 0; i < 9; ++i)
    load_lds16((const char*)gsrc + i * 1024 + lane * 16, xw + i * 1024);
  asm volatile("s_waitcnt vmcnt(0)" ::: "memory");

  // ---- A-fragments to registers (wave-private slice; no barrier needed) --
  bf16x8 af[8];
#pragma unroll
  for (int ks = 0; ks < 8; ++ks)
    af[ks] = *(const bf16x8*)&lds[wv * XWSH + l15 * XSTR + ks * 32 + quad * 8];
  __syncthreads();   // all A-reads done before w-tile overwrites lds

  floatx4 accs[3][4];
#pragma unroll
  for (int s = 0; s < 3; ++s)
#pragma unroll
    for (int i = 0; i < 4; ++i) accs[s][i] = (floatx4){0.f, 0.f, 0.f, 0.f};

#pragma unroll
  for (int s = 0; s < 3; ++s) {
    int ntile = ngrp * 3 + s;
    // stage 64x256 w-tile -> padded [64][XSTR] (coalesced global reads)
    const short* wsub = w + (size_t)ntile * 64 * EE;
#pragma unroll
    for (int i = 0; i < 8; ++i) {
      int c = threadIdx.x + i * 256;      // 0..2047 16B-chunks
      int row = c >> 5, col = (c & 31) * 8;
      *(bf16x8*)&lds[row * XSTR + col] = *(const bf16x8*)(wsub + row * EE + col);
    }
    __syncthreads();
#pragma unroll
    for (int ks = 0; ks < 8; ++ks)
#pragma unroll
      for (int ns = 0; ns < 4; ++ns) {
        bf16x8 bfr = *(const bf16x8*)&lds[(ns * 16 + l15) * XSTR + ks * 32 + quad * 8];
        accs[s][ns] = __builtin_amdgcn_mfma_f32_16x16x32_bf16(af[ks], bfr, accs[s][ns], 0, 0, 0);
      }
    __syncthreads();   // done reading w-tile before restage / cbuf reuse
  }

  // ---- epilogue per sub-ntile: bias(+scale), LDS transpose, stores ----
  short* cbuf = (short*)lds;               // 64*72 shorts, aliases lds
  int t0tok = mtile * 64;
  int b0 = t0tok / LL;
  bool uni = (b0 == (t0tok + 63) / LL) && (t0tok + 63 < MTOK);

#pragma unroll
  for (int s = 0; s < 3; ++s) {
    int ntile = ngrp * 3 + s;
    float qs = (ntile < 4) ? (SCALE * LOG2E) : 1.0f;
#pragma unroll
    for (int ns = 0; ns < 4; ++ns) {
      float bv = bias[ntile * 64 + ns * 16 + l15];
#pragma unroll
      for (int r = 0; r < 4; ++r)
        cbuf[(wv * 16 + quad * 4 + r) * 72 + ns * 16 + l15] =
            f2bf((accs[s][ns][r] + bv) * qs);
    }
    __syncthreads();

    int which = ntile >> 2;          // 0=q 1=k 2=v
    int fbase = (ntile & 3) * 64;

    if (which < 2) {
      short* dst0 = which ? k : q;
      int tl = threadIdx.x >> 2, seg = threadIdx.x & 3;
      int tok = t0tok + tl;
      if (tok < MTOK) {
        int b = uni ? b0 : tok / LL;
        int l = tok - b * LL;
        int fl = seg * 16;
        int h = (fbase + fl) >> 5;
        int d = (fbase + fl) & 31;
        size_t base = ((size_t)(b * HH + h) * LPAD + l) * DD + d;
        bf16x8 v0 = *(bf16x8*)(&cbuf[tl * 72 + fl]);
        bf16x8 v1 = *(bf16x8*)(&cbuf[tl * 72 + fl + 8]);
        *(bf16x8*)(dst0 + base) = v0;
        *(bf16x8*)(dst0 + base + 8) = v1;
      }
    } else {
      // V -> pair-interleaved fragment layout v4
      int fl = threadIdx.x >> 2, ls = threadIdx.x & 3;
      int h = (fbase + fl) >> 5;
      int d = (fbase + fl) & 31;
      int db = d >> 4, dl = d & 15;
      if (uni) {
        int l0 = t0tok - b0 * LL + ls * 16;   // 4-aligned (1900 % 4 == 0)
        short* Vb = v4 + (size_t)(b0 * HH + h) * BHST;
#pragma unroll
        for (int g4 = 0; g4 < 4; ++g4) {
          int l = l0 + g4 * 4;
          int kbp = l >> 5, half = (l >> 4) & 1, qd = (l >> 2) & 3; // l&3==0
          int tb = ls * 16 + g4 * 4;
          short4 vv;
          vv.x = cbuf[(tb + 0) * 72 + fl];
          vv.y = cbuf[(tb + 1) * 72 + fl];
          vv.z = cbuf[(tb + 2) * 72 + fl];
          vv.w = cbuf[(tb + 3) * 72 + fl];
          *(short4*)(Vb + (size_t)(kbp * 2 + db) * 512 + (dl + 16 * qd) * 8 + half * 4) = vv;
        }
      } else {
#pragma unroll
        for (int i = 0; i < 16; ++i) {
          int tl = ls * 16 + i;
          int tok = t0tok + tl;
          if (tok < MTOK) {
            int b = tok / LL;
            int l = tok - b * LL;
            int kbp = l >> 5, half = (l >> 4) & 1, qd = (l >> 2) & 3, j = l & 3;
            v4[(size_t)(b * HH + h) * BHST + (size_t)(kbp * 2 + db) * 512 +
               (dl + 16 * qd) * 8 + half * 4 + j] = cbuf[tl * 72 + fl];
          }
        }
      }
    }
    __syncthreads();   // cbuf free before next sub-ntile overwrites it
  }
}

// ---------------- Kernel B: flash attention, f=4 + paired-V loads ---------
// As R13 (f=4 key-split), but V fragments load as bf16x8 PAIRS: one 16B
// load per lane serves two PV slices (halves are register aliases via
// shufflevector). VMEM instructions per tile: 12 -> 8 (the per-CU TA/L1
// port is the remaining shared-resource suspect after occupancy x2,
// pipelining, and VALU-offload all came back flat).
__global__ __launch_bounds__(256, 2) void attn_kernel(
    const short* __restrict__ q, const short* __restrict__ k,
    const short* __restrict__ v4, short* __restrict__ ctx,
    const int* __restrict__ pad_size_p, const int* __restrict__ single_pad_p) {
  __shared__ float comb[2][64][44];   // 22,528 B; stride 44 spreads banks
  int bid = blockIdx.x;
  int bh = bid & 63, slot2 = bid >> 6;   // bh fastest -> 8 heads/XCD (L2 fit)
  int wv = threadIdx.x >> 6, lane = threadIdx.x & 63;
  int rowhalf = wv & 1, keyhalf = wv >> 1;
  int l15 = lane & 15, quad = lane >> 4;

  int ps = pad_size_p[0];
  int sp2 = 2 * single_pad_p[0];
  int t0 = ps >> 6;                  // 15
  int kb0 = t0 * 64;                 // 960

  const short* Q = q + (size_t)bh * LPAD * DD;
  const short* K = k + (size_t)bh * LPAD * DD;
  const short* V4 = v4 + (size_t)bh * BHST;
  int lane8 = lane * 8;

  int row0 = slot2 * 128 + rowhalf * 64;   // 64 rows per wave

  bf16x8 qf[4];
#pragma unroll
  for (int f = 0; f < 4; ++f)
    qf[f] = *(const bf16x8*)(Q + (size_t)(row0 + f * 16 + l15) * DD + quad * 8);

  // per-lane group window (for masking)
  int glo[4], ghi[4];
  // per-16-row-half uniform group span (for slice skipping)
  int fg_lo[4], fg_hi[4];
#pragma unroll
  for (int f = 0; f < 4; ++f) {
    int row = row0 + f * 16 + l15;
    int g = row / sp2;
    int lo = g * sp2, hi = lo + sp2;
    if (row >= ps) { lo = 0; hi = 0; }
    glo[f] = lo; ghi[f] = hi;
    int first = row0 + f * 16, last = first + 15;
    if (first >= ps) { fg_lo[f] = 0; fg_hi[f] = 0; }
    else { fg_lo[f] = (first / sp2) * sp2; fg_hi[f] = (last / sp2) * sp2 + sp2; }
  }

  const short one_bf = (short)0x3F80;              // bf16 1.0
  const bf16x4 onesf = {one_bf, one_bf, one_bf, one_bf};

  floatx4 lsum[4];
  floatx4 ot[4][2];
#pragma unroll
  for (int f = 0; f < 4; ++f) {
    lsum[f] = (floatx4){0.f, 0.f, 0.f, 0.f};
#pragma unroll
    for (int db = 0; db < 2; ++db) ot[f][db] = (floatx4){0.f, 0.f, 0.f, 0.f};
  }
  const floatx4 zf = (floatx4){0.f, 0.f, 0.f, 0.f};

  // one 64-key tile. mode: 0 = band-clean, 1 = band edge (ps/LL), 2 = group
  auto tile_work = [&](int kbase, int mode) {
    const short* vp = V4 + (size_t)(kbase >> 5) * 1024;       // pair base
    const short* kp = K + (size_t)kbase * DD + l15 * DD + quad * 8;
    bf16x8 ka[4];
    bf16x8 va8[2][2];
#pragma unroll
    for (int ns = 0; ns < 4; ++ns)
      ka[ns] = *(const bf16x8*)(kp + ns * 512);   // 16 keys * 32 shorts
#pragma unroll
    for (int db = 0; db < 2; ++db)
#pragma unroll
      for (int np = 0; np < 2; ++np)
        va8[db][np] = *(const bf16x8*)(vp + (np * 2 + db) * 512 + lane8);
    bf16x4 va[2][4];
#pragma unroll
    for (int db = 0; db < 2; ++db)
#pragma unroll
      for (int np = 0; np < 2; ++np) {
        va[db][2 * np]     = __builtin_shufflevector(va8[db][np], va8[db][np], 0, 1, 2, 3);
        va[db][2 * np + 1] = __builtin_shufflevector(va8[db][np], va8[db][np], 4, 5, 6, 7);
      }

    bool act[4][4];
    bf16x4 pt[4][4];
#pragma unroll
    for (int ns = 0; ns < 4; ++ns) {
      int ks0 = kbase + ns * 16;
#pragma unroll
      for (int f = 0; f < 4; ++f) {
        bool ov = (ks0 + 16 > fg_lo[f]) & (ks0 < fg_hi[f]);   // uniform
        bool a = true;
        if (mode == 2) a = ov;
        else if (mode == 1) a = (ks0 < LL) & ((ks0 + 16 > ps) | ov);
        act[f][ns] = a;
        if (a) {
          floatx4 st = __builtin_amdgcn_mfma_f32_16x16x32_bf16(ka[ns], qf[f], zf, 0, 0, 0);
          float e[4];
#pragma unroll
          for (int r = 0; r < 4; ++r) {
            float ev = __builtin_amdgcn_exp2f(st[r]);
            if (mode) {
              int key = ks0 + quad * 4 + r;
              int ing = (key >= glo[f]) & (key < ghi[f]);
              int vis = (mode == 2) ? ing : ((key < LL) & ((key >= ps) | ing));
              ev = vis ? ev : 0.f;
            }
            e[r] = ev;
          }
          pt[f][ns] = pack4(e[0], e[1], e[2], e[3]);
        }
      }
    }
    __builtin_amdgcn_s_setprio(1);
#pragma unroll
    for (int f = 0; f < 4; ++f)
#pragma unroll
      for (int ns = 0; ns < 4; ++ns)
        if (mode == 0 || act[f][ns]) {
          lsum[f] = __builtin_amdgcn_mfma_f32_16x16x16bf16_1k(onesf, pt[f][ns], lsum[f], 0, 0, 0);
#pragma unroll
          for (int db = 0; db < 2; ++db)
            ot[f][db] = __builtin_amdgcn_mfma_f32_16x16x16bf16_1k(va[db][ns], pt[f][ns], ot[f][db], 0, 0, 0);
        }
    __builtin_amdgcn_s_setprio(0);
  };

  // ---- group phase: keys < kb0 visible only inside own group ----
  // parity-split across keyhalf waves
  if (row0 < ps) {
    int rmaxd = row0 + 63;
    if (rmaxd >= ps) rmaxd = ps - 1;
    int c0 = (row0 / sp2) * sp2;
    int c1 = (rmaxd / sp2) * sp2 + sp2;
    if (c1 > ps) c1 = ps;
    int g_t0 = c0 >> 6;
    int g_end = (c1 + 63) >> 6;
    if (g_end > t0) g_end = t0;
    for (int jb = g_t0 + keyhalf; jb < g_end; jb += 2)
      tile_work(jb * 64, 2);
  }

  // ---- band phase: keys [kb0, LPAD), parity-split ----
  for (int kbase = kb0 + keyhalf * 64; kbase < LPAD; kbase += 128) {
    if ((kbase < ps) | (kbase + 64 > LL)) tile_work(kbase, 1);
    else tile_work(kbase, 0);
  }

  // ---- combine partials across keyhalf waves via LDS ----
  if (keyhalf == 1) {
    float* dst = &comb[rowhalf][lane][0];
#pragma unroll
    for (int f = 0; f < 4; ++f) {
      *(floatx4*)(dst + f * 8)     = ot[f][0];
      *(floatx4*)(dst + f * 8 + 4) = ot[f][1];
      dst[32 + f] = lsum[f][0];
    }
  }
  __syncthreads();
  if (keyhalf == 1) return;

  {
    const float* src = &comb[rowhalf][lane][0];
#pragma unroll
    for (int f = 0; f < 4; ++f) {
      ot[f][0] += *(const floatx4*)(src + f * 8);
      ot[f][1] += *(const floatx4*)(src + f * 8 + 4);
      lsum[f][0] += src[32 + f];
    }
  }

  int b = bh >> 3, h = bh & 7;
#pragma unroll
  for (int f = 0; f < 4; ++f) {
    int row = row0 + f * 16 + l15;
    if (row >= LL) continue;
    float inv = 1.f / lsum[f][0];      // full denominator (MFMA-summed)
    size_t base = ((size_t)b * LL + row) * EE + h * DD;
#pragma unroll
    for (int db = 0; db < 2; ++db) {
      short4 o;
      o.x = f2bf(ot[f][db][0] * inv);
      o.y = f2bf(ot[f][db][1] * inv);
      o.z = f2bf(ot[f][db][2] * inv);
      o.w = f2bf(ot[f][db][3] * inv);
      *(short4*)(ctx + base + db * 16 + quad * 4) = o;
    }
  }
}

// ---------------- Kernel C: out proj + residual + LayerNorm ---------------
// 32 rows per block (2 x 16 sequential halves): the 128-VGPR wr weight
// block loads ONCE and serves both halves -> halves ow L2 re-reads
// (124 -> 62 MB) and block count (950 -> 475).
#define OXS 260
__global__ __launch_bounds__(256) void outln_kernel(
    const short* __restrict__ ctx, const short* __restrict__ ow,
    const float* __restrict__ ob, const float* __restrict__ x,
    const float* __restrict__ lg, const float* __restrict__ lb,
    float* __restrict__ out) {
  __shared__ float xs[16 * OXS];        // residual x tile (coalesced staging)
  __shared__ float red[4][16][2];
  int wv = threadIdx.x >> 6, lane = threadIdx.x & 63;
  int l15 = lane & 15, quad = lane >> 4;

  bf16x8 wr[8][4];
#pragma unroll
  for (int ks = 0; ks < 8; ++ks)
#pragma unroll
    for (int ns = 0; ns < 4; ++ns) {
      int frow = wv * 64 + ns * 16 + l15;
      wr[ks][ns] = *(const bf16x8*)(ow + (size_t)frow * EE + ks * 32 + quad * 8);
    }
  float obv[4], lgv[4], lbv[4];
#pragma unroll
  for (int ns = 0; ns < 4; ++ns) {
    int c = wv * 64 + ns * 16 + l15;
    obv[ns] = ob[c]; lgv[ns] = lg[c]; lbv[ns] = lb[c];
  }

  for (int h2 = 0; h2 < 2; ++h2) {
    int rowbase = blockIdx.x * 32 + h2 * 16;

    float4 xv[4];
#pragma unroll
    for (int i = 0; i < 4; ++i) {
      int row = (threadIdx.x >> 6) + i * 4;
      int col = (threadIdx.x & 63) * 4;
      xv[i] = *(const float4*)(x + (size_t)(rowbase + row) * EE + col);
    }
    const short* crow = ctx + (size_t)(rowbase + l15) * EE;
    bf16x8 ca[8];
#pragma unroll
    for (int ks = 0; ks < 8; ++ks)
      ca[ks] = *(const bf16x8*)(crow + ks * 32 + quad * 8);
    asm volatile("" ::: "memory");

#pragma unroll
    for (int i = 0; i < 4; ++i) {
      int row = (threadIdx.x >> 6) + i * 4;
      int col = (threadIdx.x & 63) * 4;
      *(float4*)&xs[row * OXS + col] = xv[i];
    }
    __syncthreads();

    floatx4 acc[4];
#pragma unroll
    for (int i = 0; i < 4; ++i) acc[i] = (floatx4){0.f, 0.f, 0.f, 0.f};
#pragma unroll
    for (int ks = 0; ks < 8; ++ks)
#pragma unroll
      for (int ns = 0; ns < 4; ++ns)
        acc[ns] = __builtin_amdgcn_mfma_f32_16x16x32_bf16(ca[ks], wr[ks][ns], acc[ns], 0, 0, 0);

    float y[4][4];                       // [ns][r]
    float s1[4] = {0.f, 0.f, 0.f, 0.f}, s2[4] = {0.f, 0.f, 0.f, 0.f};
#pragma unroll
    for (int r = 0; r < 4; ++r) {
      int rr = quad * 4 + r;
#pragma unroll
      for (int ns = 0; ns < 4; ++ns) {
        int c = wv * 64 + ns * 16 + l15;
        float yy = acc[ns][r] + obv[ns] + xs[rr * OXS + c];
        y[ns][r] = yy;
        s1[r] += yy;
        s2[r] += yy * yy;
      }
    }
#pragma unroll
    for (int r = 0; r < 4; ++r) {
#pragma unroll
      for (int off = 1; off < 16; off <<= 1) {
        s1[r] += __shfl_xor(s1[r], off, 16);
        s2[r] += __shfl_xor(s2[r], off, 16);
      }
    }
    if (l15 == 0) {
#pragma unroll
      for (int r = 0; r < 4; ++r) {
        red[wv][quad * 4 + r][0] = s1[r];
        red[wv][quad * 4 + r][1] = s2[r];
      }
    }
    __syncthreads();
#pragma unroll
    for (int r = 0; r < 4; ++r) {
      int rr = quad * 4 + r;
      float t1 = 0.f, t2 = 0.f;
#pragma unroll
      for (int w2 = 0; w2 < 4; ++w2) { t1 += red[w2][rr][0]; t2 += red[w2][rr][1]; }
      float mu = t1 * (1.f / 256.f);
      float var = t2 * (1.f / 256.f) - mu * mu;
      float rs = rsqrtf(var + 1e-5f);
      int tok = rowbase + rr;
#pragma unroll
      for (int ns = 0; ns < 4; ++ns) {
        int c = wv * 64 + ns * 16 + l15;
        out[(size_t)tok * EE + c] = (y[ns][r] - mu) * rs * lgv[ns] + lbv[ns];
      }
    }
    __syncthreads();   // xs/red free before next half overwrites
  }
}

extern "C" void kernel_launch(void* const* d_in, const int* in_sizes, int n_in,
                              void* d_out, int out_size, void* d_ws, size_t ws_size,
                              hipStream_t stream) {
  const float* x  = (const float*)d_in[0];
  const float* w  = (const float*)d_in[1];
  const float* wb = (const float*)d_in[2];
  const float* ow = (const float*)d_in[3];
  const float* ob = (const float*)d_in[4];
  const float* lg = (const float*)d_in[5];
  const float* lb = (const float*)d_in[6];
  const int* ps = (const int*)d_in[8];   // pad_size
  const int* sp = (const int*)d_in[9];   // single_pad

  short* wbb = (short*)d_ws;                       // 768*256 bf16
  short* owb = wbb + (size_t)768 * EE;             // 256*256 bf16
  short* qw  = owb + (size_t)256 * EE;             // 64*1920*32 bf16 (pre-scaled)
  short* kw  = qw + (size_t)64 * LPAD * DD;
  short* v4w = kw + (size_t)64 * LPAD * DD;        // pair-interleaved V
  // xbf (15264*264 shorts, 8.06 MB) and ctx (15200*256 shorts, 7.78 MB)
  // have disjoint lifetimes -> alias them in the same workspace region.
  short* xbf = v4w + (size_t)64 * BHST;
  short* ctx = xbf;

  cvt_kernel<<<CVT_TOT / 256, 256, 0, stream>>>(w, ow, x, wbb, owb, xbf);
  qkv_kernel<<<240 * 4, 256, 0, stream>>>(xbf, wbb, wb, qw, kw, v4w);
  attn_kernel<<<15 * 64, 256, 0, stream>>>(qw, kw, v4w, ctx, ps, sp);
  outln_kernel<<<475, 256, 0, stream>>>(ctx, owb, ob, x, lg, lb, (float*)d_out);
}